// Round 4
// baseline (2900.298 us; speedup 1.0000x reference)
//
#include <hip/hip_runtime.h>

constexpr int Bc = 2, Sc = 4096, Dmc = 768, Hc = 12, HDc = 64, Wc = 256, Gc = 16;
constexpr float SCALEc = 0.125f;   // 1/sqrt(64)
constexpr float NEGc = -10000.0f;

typedef __attribute__((ext_vector_type(8))) short s16x8;
typedef __attribute__((ext_vector_type(4))) float f32x4;

#define DEVINL __device__ __forceinline__

DEVINL float b2f(short x) {
  unsigned int u = ((unsigned int)(unsigned short)x) << 16;
  return __builtin_bit_cast(float, u);
}
DEVINL short f2b(float f) {
  unsigned int u = __builtin_bit_cast(unsigned int, f);
  unsigned int r = (u + 0x7fffu + ((u >> 16) & 1u)) >> 16;
  return (short)r;
}

// ---------------- projection GEMM: Y = (bf16(X) @ bf16(W) + b) * scale -> bf16 ----
// X: [8192][768] f32, W: [768][768] f32, Y: [8192][768] bf16
// Validated: matched the correct-by-construction f32 GEMM to bf16 precision (r2==r3).
__global__ __launch_bounds__(256) void proj_gemm(
    const float* __restrict__ X, const float* __restrict__ Wm,
    const float* __restrict__ bias, short* __restrict__ Y, float scale)
{
  __shared__ short lA[64][32];
  __shared__ short lB[64][32];   // stored transposed: [n][k]
  const int tid = threadIdx.x;
  const int lane = tid & 63, wid = tid >> 6;
  const int m0 = blockIdx.x * 64, n0 = blockIdx.y * 64;
  const int wm = (wid >> 1) * 32, wn = (wid & 1) * 32;
  const int lr = lane & 15, lq = lane >> 4;

  f32x4 acc[2][2] = {};

  const int amm = tid >> 2, akk = (tid & 3) * 8;
  const int bnn = tid & 63, bkk = (tid >> 6) * 8;

  for (int k0 = 0; k0 < Dmc; k0 += 32) {
    const float* srcA = X + (size_t)(m0 + amm) * Dmc + k0 + akk;
    f32x4 x0 = *(const f32x4*)srcA;
    f32x4 x1 = *(const f32x4*)(srcA + 4);
    short tmpA[8];
#pragma unroll
    for (int u = 0; u < 4; ++u) { tmpA[u] = f2b(x0[u]); tmpA[4 + u] = f2b(x1[u]); }
    *(s16x8*)&lA[amm][akk] = *(const s16x8*)tmpA;

    short tmpB[8];
#pragma unroll
    for (int u = 0; u < 8; ++u)
      tmpB[u] = f2b(Wm[(size_t)(k0 + bkk + u) * Dmc + n0 + bnn]);
    *(s16x8*)&lB[bnn][bkk] = *(const s16x8*)tmpB;
    __syncthreads();

#pragma unroll
    for (int mi = 0; mi < 2; ++mi) {
      s16x8 av = *(const s16x8*)&lA[wm + mi * 16 + lr][lq * 8];
#pragma unroll
      for (int ni = 0; ni < 2; ++ni) {
        s16x8 bv = *(const s16x8*)&lB[wn + ni * 16 + lr][lq * 8];
        acc[mi][ni] = __builtin_amdgcn_mfma_f32_16x16x32_bf16(av, bv, acc[mi][ni], 0, 0, 0);
      }
    }
    __syncthreads();
  }

#pragma unroll
  for (int mi = 0; mi < 2; ++mi)
#pragma unroll
    for (int ni = 0; ni < 2; ++ni) {
      int col = n0 + wn + ni * 16 + lr;
      float bv_ = bias[col];
#pragma unroll
      for (int r = 0; r < 4; ++r) {
        int row = m0 + wm + mi * 16 + lq * 4 + r;
        Y[(size_t)row * Dmc + col] = f2b((acc[mi][ni][r] + bv_) * scale);
      }
    }
}

// ---------------- qg projection (only 32 rows total), f32 out ----------------
__global__ __launch_bounds__(256) void qg_proj(
    const float* __restrict__ hs, const float* __restrict__ Wqg,
    const float* __restrict__ bqg, float* __restrict__ qg)
{
  const int row = blockIdx.x;           // b*G + i
  const int b = row / Gc, i = row % Gc;
  const int tid = threadIdx.x;
  __shared__ float x[Dmc];
  for (int c = tid; c < Dmc; c += 256)
    x[c] = b2f(f2b(hs[((size_t)(b * Sc + i)) * Dmc + c]));   // bf16-round input
  __syncthreads();
  for (int n = tid; n < Dmc; n += 256) {
    float acc = bqg[n];
    for (int c = 0; c < Dmc; ++c)
      acc = fmaf(x[c], b2f(f2b(Wqg[(size_t)c * Dmc + n])), acc);
    qg[(size_t)row * Dmc + n] = acc * SCALEc;
  }
}

// ---------------- local (banded + g-selected) attention, f32 out ----------------
__global__ __launch_bounds__(256) void local_attn(
    const short* __restrict__ q, const short* __restrict__ k,
    const short* __restrict__ v, float* __restrict__ out)
{
  const int s = blockIdx.x;
  if (s < Gc) return;                    // global rows handled separately
  const int h = blockIdx.y, b = blockIdx.z;
  const int tid = threadIdx.x;
  const int lane = tid & 63, wid = tid >> 6;

  __shared__ float qrow[64];
  __shared__ float lg[544];
  __shared__ float red[8];
  __shared__ float osum[4][64];

  const size_t base = ((size_t)(b * Sc + s)) * Dmc + h * HDc;
  if (tid < 64) qrow[tid] = b2f(q[base + tid]);
  __syncthreads();

  // logits: j<16 -> global keys; j>=16 -> window key s-256+(j-16)
  for (int j = tid; j < 529; j += 256) {
    int kpos; float addv = 0.f;
    if (j < Gc) kpos = j;
    else {
      kpos = s - Wc + (j - Gc);
      if (kpos < Gc) addv = NEGc;
    }
    float val;
    if (kpos < 0 || kpos >= Sc) val = -INFINITY;
    else {
      const s16x8* kr = (const s16x8*)(k + ((size_t)(b * Sc + kpos)) * Dmc + h * HDc);
      float acc = 0.f;
#pragma unroll
      for (int c = 0; c < 8; ++c) {
        s16x8 kv = kr[c];
#pragma unroll
        for (int u = 0; u < 8; ++u) acc = fmaf(qrow[c * 8 + u], b2f(kv[u]), acc);
      }
      val = acc + addv;
    }
    lg[j] = val;
  }
  __syncthreads();

  float m = -INFINITY;
  for (int j = tid; j < 529; j += 256) m = fmaxf(m, lg[j]);
#pragma unroll
  for (int off = 32; off > 0; off >>= 1) m = fmaxf(m, __shfl_xor(m, off));
  if (lane == 0) red[wid] = m;
  __syncthreads();
  m = fmaxf(fmaxf(red[0], red[1]), fmaxf(red[2], red[3]));

  float ls = 0.f;
  for (int j = tid; j < 529; j += 256) {
    float p = __expf(lg[j] - m);
    lg[j] = p;
    ls += p;
  }
#pragma unroll
  for (int off = 32; off > 0; off >>= 1) ls += __shfl_xor(ls, off);
  if (lane == 0) red[4 + wid] = ls;
  __syncthreads();
  const float inv = 1.f / (red[4] + red[5] + red[6] + red[7]);

  const int d = tid & 63, grp = tid >> 6;
  float o = 0.f;
  for (int j = grp; j < 529; j += 4) {
    int kpos = (j < Gc) ? j : s - Wc + (j - Gc);
    if (kpos < 0 || kpos >= Sc) continue;
    o = fmaf(lg[j], b2f(v[((size_t)(b * Sc + kpos)) * Dmc + h * HDc + d]), o);
  }
  osum[grp][d] = o;
  __syncthreads();
  if (tid < 64) {
    float r = (osum[0][tid] + osum[1][tid] + osum[2][tid] + osum[3][tid]) * inv;
    out[base + tid] = r;
  }
}

// ---------------- global-token attention (rows s < g), f32 out ----------------
__global__ __launch_bounds__(256) void global_attn(
    const float* __restrict__ qg, const short* __restrict__ kg,
    const short* __restrict__ vg, float* __restrict__ out)
{
  const int i = blockIdx.x, h = blockIdx.y, b = blockIdx.z;
  const int tid = threadIdx.x, lane = tid & 63, wid = tid >> 6;
  __shared__ float qrow[64];
  __shared__ float lg[Sc];
  __shared__ float red[8];
  __shared__ float osum[4][64];

  if (tid < 64) qrow[tid] = qg[((size_t)(b * Gc + i)) * Dmc + h * HDc + tid];
  __syncthreads();

  for (int sk = tid; sk < Sc; sk += 256) {
    const s16x8* kr = (const s16x8*)(kg + ((size_t)(b * Sc + sk)) * Dmc + h * HDc);
    float acc = 0.f;
#pragma unroll
    for (int c = 0; c < 8; ++c) {
      s16x8 kv = kr[c];
#pragma unroll
      for (int u = 0; u < 8; ++u) acc = fmaf(qrow[c * 8 + u], b2f(kv[u]), acc);
    }
    lg[sk] = acc;
  }
  __syncthreads();

  float m = -INFINITY;
  for (int sk = tid; sk < Sc; sk += 256) m = fmaxf(m, lg[sk]);
#pragma unroll
  for (int off = 32; off > 0; off >>= 1) m = fmaxf(m, __shfl_xor(m, off));
  if (lane == 0) red[wid] = m;
  __syncthreads();
  m = fmaxf(fmaxf(red[0], red[1]), fmaxf(red[2], red[3]));

  float ls = 0.f;
  for (int sk = tid; sk < Sc; sk += 256) {
    float p = __expf(lg[sk] - m);
    lg[sk] = p;
    ls += p;
  }
#pragma unroll
  for (int off = 32; off > 0; off >>= 1) ls += __shfl_xor(ls, off);
  if (lane == 0) red[4 + wid] = ls;
  __syncthreads();
  const float inv = 1.f / (red[4] + red[5] + red[6] + red[7]);

  const int d = tid & 63, grp = tid >> 6;
  float o = 0.f;
  for (int sk = grp; sk < Sc; sk += 4)
    o = fmaf(lg[sk], b2f(vg[((size_t)(b * Sc + sk)) * Dmc + h * HDc + d]), o);
  osum[grp][d] = o;
  __syncthreads();
  if (tid < 64) {
    float r = (osum[0][tid] + osum[1][tid] + osum[2][tid] + osum[3][tid]) * inv;
    out[((size_t)(b * Sc + i)) * Dmc + h * HDc + tid] = r;
  }
}

extern "C" void kernel_launch(void* const* d_in, const int* in_sizes, int n_in,
                              void* d_out, int out_size, void* d_ws, size_t ws_size,
                              hipStream_t stream) {
  const float* hs  = (const float*)d_in[0];
  const float* Wq  = (const float*)d_in[1];
  const float* bq  = (const float*)d_in[2];
  const float* Wk  = (const float*)d_in[3];
  const float* bk  = (const float*)d_in[4];
  const float* Wv  = (const float*)d_in[5];
  const float* bv  = (const float*)d_in[6];
  const float* Wqg = (const float*)d_in[7];
  const float* bqg = (const float*)d_in[8];
  const float* Wkg = (const float*)d_in[9];
  const float* bkg = (const float*)d_in[10];
  const float* Wvg = (const float*)d_in[11];
  const float* bvg = (const float*)d_in[12];
  float* out = (float*)d_out;            // f32 output buffer (r2/r3 fingerprint)

  char* ws = (char*)d_ws;
  const size_t bufB = (size_t)Bc * Sc * Dmc * sizeof(short);   // 12.58 MB
  short* qb = (short*)(ws);
  short* kb = (short*)(ws + bufB);
  short* vb = (short*)(ws + 2 * bufB);
  float* qg = (float*)(ws + 3 * bufB);   // 98 KB

  dim3 gg(Bc * Sc / 64, Dmc / 64), bb(256);
  proj_gemm<<<gg, bb, 0, stream>>>(hs, Wq, bq, qb, SCALEc);
  proj_gemm<<<gg, bb, 0, stream>>>(hs, Wk, bk, kb, 1.0f);
  proj_gemm<<<gg, bb, 0, stream>>>(hs, Wv, bv, vb, 1.0f);
  qg_proj<<<dim3(Bc * Gc), bb, 0, stream>>>(hs, Wqg, bqg, qg);

  local_attn<<<dim3(Sc, Hc, Bc), bb, 0, stream>>>(qb, kb, vb, out);

  // reuse q/k buffers for the global-path projections
  proj_gemm<<<gg, bb, 0, stream>>>(hs, Wkg, bkg, qb, 1.0f);
  proj_gemm<<<gg, bb, 0, stream>>>(hs, Wvg, bvg, kb, 1.0f);
  global_attn<<<dim3(Gc, Hc, Bc), bb, 0, stream>>>(qg, qb, kb, out);
}

// Round 5
// 719.637 us; speedup vs baseline: 4.0302x; 4.0302x over previous
//
#include <hip/hip_runtime.h>

constexpr int Bc = 2, Sc = 4096, Dmc = 768, Hc = 12, HDc = 64, Wc = 256, Gc = 16;
constexpr float SCALEc = 0.125f;   // 1/sqrt(64)
constexpr float NEGc = -10000.0f;

typedef __attribute__((ext_vector_type(8))) short s16x8;
typedef __attribute__((ext_vector_type(4))) float f32x4;

#define DEVINL __device__ __forceinline__

DEVINL float b2f(short x) {
  unsigned int u = ((unsigned int)(unsigned short)x) << 16;
  return __builtin_bit_cast(float, u);
}
DEVINL short f2b(float f) {
  unsigned int u = __builtin_bit_cast(unsigned int, f);
  unsigned int r = (u + 0x7fffu + ((u >> 16) & 1u)) >> 16;
  return (short)r;
}

// ---------------- projection GEMM: Y = (bf16(X) @ bf16(W) + b) * scale -> bf16 ----
__global__ __launch_bounds__(256) void proj_gemm(
    const float* __restrict__ X, const float* __restrict__ Wm,
    const float* __restrict__ bias, short* __restrict__ Y, float scale)
{
  __shared__ short lA[64][32];
  __shared__ short lB[64][32];   // stored transposed: [n][k]
  const int tid = threadIdx.x;
  const int lane = tid & 63, wid = tid >> 6;
  const int m0 = blockIdx.x * 64, n0 = blockIdx.y * 64;
  const int wm = (wid >> 1) * 32, wn = (wid & 1) * 32;
  const int lr = lane & 15, lq = lane >> 4;

  f32x4 acc[2][2] = {};

  const int amm = tid >> 2, akk = (tid & 3) * 8;
  const int bnn = tid & 63, bkk = (tid >> 6) * 8;

  for (int k0 = 0; k0 < Dmc; k0 += 32) {
    const float* srcA = X + (size_t)(m0 + amm) * Dmc + k0 + akk;
    f32x4 x0 = *(const f32x4*)srcA;
    f32x4 x1 = *(const f32x4*)(srcA + 4);
    short tmpA[8];
#pragma unroll
    for (int u = 0; u < 4; ++u) { tmpA[u] = f2b(x0[u]); tmpA[4 + u] = f2b(x1[u]); }
    *(s16x8*)&lA[amm][akk] = *(const s16x8*)tmpA;

    short tmpB[8];
#pragma unroll
    for (int u = 0; u < 8; ++u)
      tmpB[u] = f2b(Wm[(size_t)(k0 + bkk + u) * Dmc + n0 + bnn]);
    *(s16x8*)&lB[bnn][bkk] = *(const s16x8*)tmpB;
    __syncthreads();

#pragma unroll
    for (int mi = 0; mi < 2; ++mi) {
      s16x8 av = *(const s16x8*)&lA[wm + mi * 16 + lr][lq * 8];
#pragma unroll
      for (int ni = 0; ni < 2; ++ni) {
        s16x8 bv = *(const s16x8*)&lB[wn + ni * 16 + lr][lq * 8];
        acc[mi][ni] = __builtin_amdgcn_mfma_f32_16x16x32_bf16(av, bv, acc[mi][ni], 0, 0, 0);
      }
    }
    __syncthreads();
  }

#pragma unroll
  for (int mi = 0; mi < 2; ++mi)
#pragma unroll
    for (int ni = 0; ni < 2; ++ni) {
      int col = n0 + wn + ni * 16 + lr;
      float bv_ = bias[col];
#pragma unroll
      for (int r = 0; r < 4; ++r) {
        int row = m0 + wm + mi * 16 + lq * 4 + r;
        Y[(size_t)row * Dmc + col] = f2b((acc[mi][ni][r] + bv_) * scale);
      }
    }
}

// ---------------- qg projection (only 32 rows total), f32 out ----------------
__global__ __launch_bounds__(256) void qg_proj(
    const float* __restrict__ hs, const float* __restrict__ Wqg,
    const float* __restrict__ bqg, float* __restrict__ qg)
{
  const int row = blockIdx.x;           // b*G + i
  const int b = row / Gc, i = row % Gc;
  const int tid = threadIdx.x;
  __shared__ float x[Dmc];
  for (int c = tid; c < Dmc; c += 256)
    x[c] = b2f(f2b(hs[((size_t)(b * Sc + i)) * Dmc + c]));
  __syncthreads();
  for (int n = tid; n < Dmc; n += 256) {
    float acc = bqg[n];
    for (int c = 0; c < Dmc; ++c)
      acc = fmaf(x[c], b2f(f2b(Wqg[(size_t)c * Dmc + n])), acc);
    qg[(size_t)row * Dmc + n] = acc * SCALEc;
  }
}

// ---------------- MFMA banded attention ----------------
// Block: 4 waves, 64 queries (q0..q0+63) of one (b,h). Column space: 608 cols
// = 19 chunks x 32: cols 0..15 = global keys (sel, unmasked), 16..591 = window
// keys q0-256+(c-16), 592..607 dead. S^T = mfma(K,Q) so per-query reduce is
// shfl_xor(16/32); online softmax; P via swizzled LDS roundtrip; PV mfma.
__global__ __launch_bounds__(256) void local_attn_mfma(
    const short* __restrict__ q, const short* __restrict__ k,
    const short* __restrict__ v, float* __restrict__ out)
{
  const int q0 = blockIdx.x * 64;
  const int h = blockIdx.y, b = blockIdx.z;
  const int tid = threadIdx.x, lane = tid & 63, wid = tid >> 6;

  __shared__ short Ks[2048];      // [32 key][64 d] bf16, XOR-swizzled
  __shared__ short Vt[2048];      // [64 d][32 key] bf16, XOR-swizzled
  __shared__ short Ps[4][512];    // per-wave [16 q][32 k] bf16, XOR-swizzled

  const int ql = lane & 15;       // frag row/col index
  const int lg = lane >> 4;       // lane group
  const int qr = wid * 16 + ql;   // query within 64-block (mask side)

  // Q fragment (B-frag layout): lane holds Q[q0+qr][lg*8 + sl*32 + j]
  s16x8 qf[2];
  {
    const short* qp = q + ((size_t)(b * Sc + q0 + qr)) * Dmc + h * HDc + lg * 8;
    qf[0] = *(const s16x8*)qp;
    qf[1] = *(const s16x8*)(qp + 32);
  }

  f32x4 oacc[4] = {};             // O[q=lg*4+rr][d=dt*16+ql]
  float m_run = -INFINITY, l_run = 0.f;

  const int skr = tid >> 3;            // 0..31: key row (K) / key col (Vt)
  const int sdb = (tid & 7) * 8;       // d block

  for (int ch = 0; ch < 19; ++ch) {
    // ---- stage K and V^T for this 32-key chunk ----
    {
      int col = ch * 32 + skr;
      int key = (col < Gc) ? col : q0 - Wc + (col - Gc);
      int kc = min(max(key, 0), Sc - 1);
      const size_t rb = ((size_t)(b * Sc + kc)) * Dmc + h * HDc + sdb;
      s16x8 kv = *(const s16x8*)(k + rb);
      s16x8 vv = *(const s16x8*)(v + rb);
      int kbyte = (skr * 128 + sdb * 2) ^ ((skr & 7) << 4);
      *(s16x8*)((char*)Ks + kbyte) = kv;
#pragma unroll
      for (int j = 0; j < 8; ++j) {
        int d = sdb + j;
        int vbyte = (d * 64 + skr * 2) ^ ((d & 3) << 4);
        *(short*)((char*)Vt + vbyte) = vv[j];
      }
    }
    __syncthreads();

    // ---- S^T tiles: D[k][q], 2 tiles of 16 keys ----
    f32x4 sac[2] = {};
#pragma unroll
    for (int kt = 0; kt < 2; ++kt) {
      int row = kt * 16 + ql;
#pragma unroll
      for (int sl = 0; sl < 2; ++sl) {
        int byte_ = (row * 128 + (lg * 8 + sl * 32) * 2) ^ ((row & 7) << 4);
        s16x8 af = *(const s16x8*)((const char*)Ks + byte_);
        sac[kt] = __builtin_amdgcn_mfma_f32_16x16x32_bf16(af, qf[sl], sac[kt], 0, 0, 0);
      }
    }

    // ---- mask: lane holds q=ql, k=(lg*4+r) within tile ----
#pragma unroll
    for (int kt = 0; kt < 2; ++kt)
#pragma unroll
      for (int r = 0; r < 4; ++r) {
        int c = ch * 32 + kt * 16 + lg * 4 + r;
        if (c >= Gc) {
          float sv = sac[kt][r];
          int jj = c - Gc - qr;
          int kp2 = q0 - Wc + (c - Gc);
          bool ok = (jj >= 0) & (jj <= 2 * Wc) & (kp2 >= 0) & (kp2 < Sc);
          sac[kt][r] = ok ? (sv + ((kp2 < Gc) ? NEGc : 0.f)) : -INFINITY;
        }
      }

    // ---- online softmax (per-query stats live at lane&15==q) ----
    float cm = -INFINITY;
#pragma unroll
    for (int kt = 0; kt < 2; ++kt)
#pragma unroll
      for (int r = 0; r < 4; ++r) cm = fmaxf(cm, sac[kt][r]);
    cm = fmaxf(cm, __shfl_xor(cm, 16));
    cm = fmaxf(cm, __shfl_xor(cm, 32));
    float m_new = fmaxf(m_run, cm);
    float scale = __expf(m_run - m_new);   // chunk0: exp(-inf - finite) = 0
    float cl = 0.f;
#pragma unroll
    for (int kt = 0; kt < 2; ++kt)
#pragma unroll
      for (int r = 0; r < 4; ++r) {
        float p = __expf(sac[kt][r] - m_new);
        sac[kt][r] = p;
        cl += p;
      }
    cl += __shfl_xor(cl, 16);
    cl += __shfl_xor(cl, 32);
    l_run = l_run * scale + cl;
    m_run = m_new;

    // rescale O (O rows q = lg*4+rr; scale held at lane q)
#pragma unroll
    for (int rr = 0; rr < 4; ++rr) {
      float os = __shfl(scale, lg * 4 + rr);
#pragma unroll
      for (int dt = 0; dt < 4; ++dt) oacc[dt][rr] *= os;
    }

    // ---- P -> bf16 via per-wave swizzled LDS (C-frag -> A-frag relayout) ----
#pragma unroll
    for (int kt = 0; kt < 2; ++kt)
#pragma unroll
      for (int r = 0; r < 4; ++r) {
        int kk = kt * 16 + lg * 4 + r;
        int byte_ = (ql * 64 + kk * 2) ^ ((ql & 3) << 4);
        *(short*)((char*)Ps[wid] + byte_) = f2b(sac[kt][r]);
      }
    {
      int pbyte = (ql * 64 + lg * 16) ^ ((ql & 3) << 4);
      s16x8 pf = *(const s16x8*)((const char*)Ps[wid] + pbyte);
#pragma unroll
      for (int dt = 0; dt < 4; ++dt) {
        int d = dt * 16 + ql;
        int vbyte = (d * 64 + lg * 16) ^ ((d & 3) << 4);
        s16x8 vf = *(const s16x8*)((const char*)Vt + vbyte);
        oacc[dt] = __builtin_amdgcn_mfma_f32_16x16x32_bf16(pf, vf, oacc[dt], 0, 0, 0);
      }
    }
    __syncthreads();
  }

  // ---- epilogue: O/l, f32 store ----
  float inv = 1.f / l_run;
#pragma unroll
  for (int rr = 0; rr < 4; ++rr) {
    float oi = __shfl(inv, lg * 4 + rr);
    int row = q0 + wid * 16 + lg * 4 + rr;
    float* op = out + ((size_t)(b * Sc + row)) * Dmc + h * HDc + ql;
#pragma unroll
    for (int dt = 0; dt < 4; ++dt)
      op[dt * 16] = oacc[dt][rr] * oi;
  }
}

// ---------------- global-token attention (rows s < g), f32 out ----------------
__global__ __launch_bounds__(256) void global_attn(
    const float* __restrict__ qg, const short* __restrict__ kg,
    const short* __restrict__ vg, float* __restrict__ out)
{
  const int i = blockIdx.x, h = blockIdx.y, b = blockIdx.z;
  const int tid = threadIdx.x, lane = tid & 63, wid = tid >> 6;
  __shared__ float qrow[64];
  __shared__ float lg[Sc];
  __shared__ float red[8];
  __shared__ float osum[4][64];

  if (tid < 64) qrow[tid] = qg[((size_t)(b * Gc + i)) * Dmc + h * HDc + tid];
  __syncthreads();

  for (int sk = tid; sk < Sc; sk += 256) {
    const s16x8* kr = (const s16x8*)(kg + ((size_t)(b * Sc + sk)) * Dmc + h * HDc);
    float acc = 0.f;
#pragma unroll
    for (int c = 0; c < 8; ++c) {
      s16x8 kv = kr[c];
#pragma unroll
      for (int u = 0; u < 8; ++u) acc = fmaf(qrow[c * 8 + u], b2f(kv[u]), acc);
    }
    lg[sk] = acc;
  }
  __syncthreads();

  float m = -INFINITY;
  for (int sk = tid; sk < Sc; sk += 256) m = fmaxf(m, lg[sk]);
#pragma unroll
  for (int off = 32; off > 0; off >>= 1) m = fmaxf(m, __shfl_xor(m, off));
  if (lane == 0) red[wid] = m;
  __syncthreads();
  m = fmaxf(fmaxf(red[0], red[1]), fmaxf(red[2], red[3]));

  float ls = 0.f;
  for (int sk = tid; sk < Sc; sk += 256) {
    float p = __expf(lg[sk] - m);
    lg[sk] = p;
    ls += p;
  }
#pragma unroll
  for (int off = 32; off > 0; off >>= 1) ls += __shfl_xor(ls, off);
  if (lane == 0) red[4 + wid] = ls;
  __syncthreads();
  const float inv = 1.f / (red[4] + red[5] + red[6] + red[7]);

  const int d = tid & 63, grp = tid >> 6;
  float o = 0.f;
  for (int sk = grp; sk < Sc; sk += 4)
    o = fmaf(lg[sk], b2f(vg[((size_t)(b * Sc + sk)) * Dmc + h * HDc + d]), o);
  osum[grp][d] = o;
  __syncthreads();
  if (tid < 64) {
    float r = (osum[0][tid] + osum[1][tid] + osum[2][tid] + osum[3][tid]) * inv;
    out[((size_t)(b * Sc + i)) * Dmc + h * HDc + tid] = r;
  }
}

extern "C" void kernel_launch(void* const* d_in, const int* in_sizes, int n_in,
                              void* d_out, int out_size, void* d_ws, size_t ws_size,
                              hipStream_t stream) {
  const float* hs  = (const float*)d_in[0];
  const float* Wq  = (const float*)d_in[1];
  const float* bq  = (const float*)d_in[2];
  const float* Wk  = (const float*)d_in[3];
  const float* bk  = (const float*)d_in[4];
  const float* Wv  = (const float*)d_in[5];
  const float* bv  = (const float*)d_in[6];
  const float* Wqg = (const float*)d_in[7];
  const float* bqg = (const float*)d_in[8];
  const float* Wkg = (const float*)d_in[9];
  const float* bkg = (const float*)d_in[10];
  const float* Wvg = (const float*)d_in[11];
  const float* bvg = (const float*)d_in[12];
  float* out = (float*)d_out;

  char* ws = (char*)d_ws;
  const size_t bufB = (size_t)Bc * Sc * Dmc * sizeof(short);   // 12.58 MB
  short* qb = (short*)(ws);
  short* kb = (short*)(ws + bufB);
  short* vb = (short*)(ws + 2 * bufB);
  float* qg = (float*)(ws + 3 * bufB);   // 98 KB

  dim3 gg(Bc * Sc / 64, Dmc / 64), bb(256);
  proj_gemm<<<gg, bb, 0, stream>>>(hs, Wq, bq, qb, SCALEc);
  proj_gemm<<<gg, bb, 0, stream>>>(hs, Wk, bk, kb, 1.0f);
  proj_gemm<<<gg, bb, 0, stream>>>(hs, Wv, bv, vb, 1.0f);
  qg_proj<<<dim3(Bc * Gc), bb, 0, stream>>>(hs, Wqg, bqg, qg);

  local_attn_mfma<<<dim3(Sc / 64, Hc, Bc), bb, 0, stream>>>(qb, kb, vb, out);

  // reuse q/k buffers for the global-path projections
  proj_gemm<<<gg, bb, 0, stream>>>(hs, Wkg, bkg, qb, 1.0f);
  proj_gemm<<<gg, bb, 0, stream>>>(hs, Wvg, bvg, kb, 1.0f);
  global_attn<<<dim3(Gc, Hc, Bc), bb, 0, stream>>>(qg, qb, kb, out);
}

// Round 6
// 384.878 us; speedup vs baseline: 7.5356x; 1.8698x over previous
//
#include <hip/hip_runtime.h>

constexpr int Bc = 2, Sc = 4096, Dmc = 768, Hc = 12, HDc = 64, Wc = 256, Gc = 16;
constexpr int NCH = 16, CHK = 256;     // split-K for global rows: 16 chunks x 256 keys
constexpr float SCALEc = 0.125f;   // 1/sqrt(64)
constexpr float NEGc = -10000.0f;

typedef __attribute__((ext_vector_type(8))) short s16x8;
typedef __attribute__((ext_vector_type(4))) float f32x4;

#define DEVINL __device__ __forceinline__

DEVINL float b2f(short x) {
  unsigned int u = ((unsigned int)(unsigned short)x) << 16;
  return __builtin_bit_cast(float, u);
}
DEVINL short f2b(float f) {
  unsigned int u = __builtin_bit_cast(unsigned int, f);
  unsigned int r = (u + 0x7fffu + ((u >> 16) & 1u)) >> 16;
  return (short)r;
}

// ---------------- projection GEMM: Y = (bf16(X) @ bf16(W) + b) * scale -> bf16 ----
__global__ __launch_bounds__(256) void proj_gemm(
    const float* __restrict__ X, const float* __restrict__ Wm,
    const float* __restrict__ bias, short* __restrict__ Y, float scale)
{
  __shared__ short lA[64][32];
  __shared__ short lB[64][32];   // stored transposed: [n][k]
  const int tid = threadIdx.x;
  const int lane = tid & 63, wid = tid >> 6;
  const int m0 = blockIdx.x * 64, n0 = blockIdx.y * 64;
  const int wm = (wid >> 1) * 32, wn = (wid & 1) * 32;
  const int lr = lane & 15, lq = lane >> 4;

  f32x4 acc[2][2] = {};

  const int amm = tid >> 2, akk = (tid & 3) * 8;
  const int bnn = tid & 63, bkk = (tid >> 6) * 8;

  for (int k0 = 0; k0 < Dmc; k0 += 32) {
    const float* srcA = X + (size_t)(m0 + amm) * Dmc + k0 + akk;
    f32x4 x0 = *(const f32x4*)srcA;
    f32x4 x1 = *(const f32x4*)(srcA + 4);
    short tmpA[8];
#pragma unroll
    for (int u = 0; u < 4; ++u) { tmpA[u] = f2b(x0[u]); tmpA[4 + u] = f2b(x1[u]); }
    *(s16x8*)&lA[amm][akk] = *(const s16x8*)tmpA;

    short tmpB[8];
#pragma unroll
    for (int u = 0; u < 8; ++u)
      tmpB[u] = f2b(Wm[(size_t)(k0 + bkk + u) * Dmc + n0 + bnn]);
    *(s16x8*)&lB[bnn][bkk] = *(const s16x8*)tmpB;
    __syncthreads();

#pragma unroll
    for (int mi = 0; mi < 2; ++mi) {
      s16x8 av = *(const s16x8*)&lA[wm + mi * 16 + lr][lq * 8];
#pragma unroll
      for (int ni = 0; ni < 2; ++ni) {
        s16x8 bv = *(const s16x8*)&lB[wn + ni * 16 + lr][lq * 8];
        acc[mi][ni] = __builtin_amdgcn_mfma_f32_16x16x32_bf16(av, bv, acc[mi][ni], 0, 0, 0);
      }
    }
    __syncthreads();
  }

#pragma unroll
  for (int mi = 0; mi < 2; ++mi)
#pragma unroll
    for (int ni = 0; ni < 2; ++ni) {
      int col = n0 + wn + ni * 16 + lr;
      float bv_ = bias[col];
#pragma unroll
      for (int r = 0; r < 4; ++r) {
        int row = m0 + wm + mi * 16 + lq * 4 + r;
        Y[(size_t)row * Dmc + col] = f2b((acc[mi][ni][r] + bv_) * scale);
      }
    }
}

// ---------------- qg projection (32 rows), more parallel: 1 col/thread ----------
__global__ __launch_bounds__(256) void qg_proj(
    const float* __restrict__ hs, const float* __restrict__ Wqg,
    const float* __restrict__ bqg, float* __restrict__ qg)
{
  const int row = blockIdx.x;           // b*G + i
  const int b = row / Gc, i = row % Gc;
  const int n = blockIdx.y * 256 + threadIdx.x;
  const int tid = threadIdx.x;
  __shared__ float x[Dmc];
  for (int c = tid; c < Dmc; c += 256)
    x[c] = b2f(f2b(hs[((size_t)(b * Sc + i)) * Dmc + c]));
  __syncthreads();
  float acc = bqg[n];
  for (int c = 0; c < Dmc; ++c)
    acc = fmaf(x[c], b2f(f2b(Wqg[(size_t)c * Dmc + n])), acc);
  qg[(size_t)row * Dmc + n] = acc * SCALEc;
}

// ---------------- MFMA banded attention ----------------
__global__ __launch_bounds__(256) void local_attn_mfma(
    const short* __restrict__ q, const short* __restrict__ k,
    const short* __restrict__ v, float* __restrict__ out)
{
  const int q0 = blockIdx.x * 64;
  const int h = blockIdx.y, b = blockIdx.z;
  const int tid = threadIdx.x, lane = tid & 63, wid = tid >> 6;

  __shared__ short Ks[2048];      // [32 key][64 d] bf16, XOR-swizzled
  __shared__ short Vt[2048];      // [64 d][32 key] bf16, XOR-swizzled
  __shared__ short Ps[4][512];    // per-wave [16 q][32 k] bf16, XOR-swizzled

  const int ql = lane & 15;
  const int lg = lane >> 4;
  const int qr = wid * 16 + ql;

  s16x8 qf[2];
  {
    const short* qp = q + ((size_t)(b * Sc + q0 + qr)) * Dmc + h * HDc + lg * 8;
    qf[0] = *(const s16x8*)qp;
    qf[1] = *(const s16x8*)(qp + 32);
  }

  f32x4 oacc[4] = {};
  float m_run = -INFINITY, l_run = 0.f;

  const int skr = tid >> 3;
  const int sdb = (tid & 7) * 8;

  for (int ch = 0; ch < 19; ++ch) {
    {
      int col = ch * 32 + skr;
      int key = (col < Gc) ? col : q0 - Wc + (col - Gc);
      int kc = min(max(key, 0), Sc - 1);
      const size_t rb = ((size_t)(b * Sc + kc)) * Dmc + h * HDc + sdb;
      s16x8 kv = *(const s16x8*)(k + rb);
      s16x8 vv = *(const s16x8*)(v + rb);
      int kbyte = (skr * 128 + sdb * 2) ^ ((skr & 7) << 4);
      *(s16x8*)((char*)Ks + kbyte) = kv;
#pragma unroll
      for (int j = 0; j < 8; ++j) {
        int d = sdb + j;
        int vbyte = (d * 64 + skr * 2) ^ ((d & 3) << 4);
        *(short*)((char*)Vt + vbyte) = vv[j];
      }
    }
    __syncthreads();

    f32x4 sac[2] = {};
#pragma unroll
    for (int kt = 0; kt < 2; ++kt) {
      int row = kt * 16 + ql;
#pragma unroll
      for (int sl = 0; sl < 2; ++sl) {
        int byte_ = (row * 128 + (lg * 8 + sl * 32) * 2) ^ ((row & 7) << 4);
        s16x8 af = *(const s16x8*)((const char*)Ks + byte_);
        sac[kt] = __builtin_amdgcn_mfma_f32_16x16x32_bf16(af, qf[sl], sac[kt], 0, 0, 0);
      }
    }

#pragma unroll
    for (int kt = 0; kt < 2; ++kt)
#pragma unroll
      for (int r = 0; r < 4; ++r) {
        int c = ch * 32 + kt * 16 + lg * 4 + r;
        if (c >= Gc) {
          float sv = sac[kt][r];
          int jj = c - Gc - qr;
          int kp2 = q0 - Wc + (c - Gc);
          bool ok = (jj >= 0) & (jj <= 2 * Wc) & (kp2 >= 0) & (kp2 < Sc);
          sac[kt][r] = ok ? (sv + ((kp2 < Gc) ? NEGc : 0.f)) : -INFINITY;
        }
      }

    float cm = -INFINITY;
#pragma unroll
    for (int kt = 0; kt < 2; ++kt)
#pragma unroll
      for (int r = 0; r < 4; ++r) cm = fmaxf(cm, sac[kt][r]);
    cm = fmaxf(cm, __shfl_xor(cm, 16));
    cm = fmaxf(cm, __shfl_xor(cm, 32));
    float m_new = fmaxf(m_run, cm);
    float scale = __expf(m_run - m_new);
    float cl = 0.f;
#pragma unroll
    for (int kt = 0; kt < 2; ++kt)
#pragma unroll
      for (int r = 0; r < 4; ++r) {
        float p = __expf(sac[kt][r] - m_new);
        sac[kt][r] = p;
        cl += p;
      }
    cl += __shfl_xor(cl, 16);
    cl += __shfl_xor(cl, 32);
    l_run = l_run * scale + cl;
    m_run = m_new;

#pragma unroll
    for (int rr = 0; rr < 4; ++rr) {
      float os = __shfl(scale, lg * 4 + rr);
#pragma unroll
      for (int dt = 0; dt < 4; ++dt) oacc[dt][rr] *= os;
    }

#pragma unroll
    for (int kt = 0; kt < 2; ++kt)
#pragma unroll
      for (int r = 0; r < 4; ++r) {
        int kk = kt * 16 + lg * 4 + r;
        int byte_ = (ql * 64 + kk * 2) ^ ((ql & 3) << 4);
        *(short*)((char*)Ps[wid] + byte_) = f2b(sac[kt][r]);
      }
    {
      int pbyte = (ql * 64 + lg * 16) ^ ((ql & 3) << 4);
      s16x8 pf = *(const s16x8*)((const char*)Ps[wid] + pbyte);
#pragma unroll
      for (int dt = 0; dt < 4; ++dt) {
        int d = dt * 16 + ql;
        int vbyte = (d * 64 + lg * 16) ^ ((d & 3) << 4);
        s16x8 vf = *(const s16x8*)((const char*)Vt + vbyte);
        oacc[dt] = __builtin_amdgcn_mfma_f32_16x16x32_bf16(pf, vf, oacc[dt], 0, 0, 0);
      }
    }
    __syncthreads();
  }

  float inv = 1.f / l_run;
#pragma unroll
  for (int rr = 0; rr < 4; ++rr) {
    float oi = __shfl(inv, lg * 4 + rr);
    int row = q0 + wid * 16 + lg * 4 + rr;
    float* op = out + ((size_t)(b * Sc + row)) * Dmc + h * HDc + ql;
#pragma unroll
    for (int dt = 0; dt < 4; ++dt)
      op[dt * 16] = oacc[dt][rr] * oi;
  }
}

// ---------------- global rows, split-K phase A: partial (m,l,O) per 256-key chunk ----
__global__ __launch_bounds__(256) void global_attn_part(
    const float* __restrict__ qg, const short* __restrict__ kg,
    const short* __restrict__ vg, float* __restrict__ pml, float* __restrict__ po)
{
  const int ch = blockIdx.x & (NCH - 1);
  const int i  = blockIdx.x >> 4;
  const int h = blockIdx.y, b = blockIdx.z;
  const int tid = threadIdx.x, lane = tid & 63, wid = tid >> 6;

  __shared__ float qrow[64];
  __shared__ float pls[CHK];
  __shared__ float red[8];
  __shared__ float osum[4][64];

  if (tid < 64) qrow[tid] = qg[(size_t)(b * Gc + i) * Dmc + h * HDc + tid];
  __syncthreads();

  // one key per thread
  const int sk = ch * CHK + tid;
  const s16x8* kr = (const s16x8*)(kg + ((size_t)(b * Sc + sk)) * Dmc + h * HDc);
  float acc = 0.f;
#pragma unroll
  for (int c = 0; c < 8; ++c) {
    s16x8 kv = kr[c];
#pragma unroll
    for (int u = 0; u < 8; ++u) acc = fmaf(qrow[c * 8 + u], b2f(kv[u]), acc);
  }

  float m = acc;
#pragma unroll
  for (int off = 32; off > 0; off >>= 1) m = fmaxf(m, __shfl_xor(m, off));
  if (lane == 0) red[wid] = m;
  __syncthreads();
  m = fmaxf(fmaxf(red[0], red[1]), fmaxf(red[2], red[3]));

  float p = __expf(acc - m);
  pls[tid] = p;
  float ls = p;
#pragma unroll
  for (int off = 32; off > 0; off >>= 1) ls += __shfl_xor(ls, off);
  if (lane == 0) red[4 + wid] = ls;
  __syncthreads();
  const float l = red[4] + red[5] + red[6] + red[7];

  const int d = tid & 63, grp = tid >> 6;
  float o = 0.f;
  for (int j = grp; j < CHK; j += 4)
    o = fmaf(pls[j], b2f(vg[((size_t)(b * Sc + ch * CHK + j)) * Dmc + h * HDc + d]), o);
  osum[grp][d] = o;
  __syncthreads();

  const size_t slot = (((size_t)(b * Hc + h) * Gc + i) * NCH + ch);
  if (tid < 64)
    po[slot * 64 + tid] = osum[0][tid] + osum[1][tid] + osum[2][tid] + osum[3][tid];
  if (tid == 0) { pml[slot * 2] = m; pml[slot * 2 + 1] = l; }
}

// ---------------- global rows, split-K phase B: combine 16 partials ----------------
__global__ __launch_bounds__(64) void global_attn_comb(
    const float* __restrict__ pml, const float* __restrict__ po,
    float* __restrict__ out)
{
  const int i = blockIdx.x, h = blockIdx.y, b = blockIdx.z;
  const int d = threadIdx.x;
  const size_t base = ((size_t)(b * Hc + h) * Gc + i) * NCH;

  float m = -INFINITY;
#pragma unroll
  for (int ch = 0; ch < NCH; ++ch) m = fmaxf(m, pml[(base + ch) * 2]);
  float l = 0.f, o = 0.f;
#pragma unroll
  for (int ch = 0; ch < NCH; ++ch) {
    float wgt = __expf(pml[(base + ch) * 2] - m);
    l = fmaf(pml[(base + ch) * 2 + 1], wgt, l);
    o = fmaf(po[(base + ch) * 64 + d], wgt, o);
  }
  out[((size_t)(b * Sc + i)) * Dmc + h * HDc + d] = o / l;
}

extern "C" void kernel_launch(void* const* d_in, const int* in_sizes, int n_in,
                              void* d_out, int out_size, void* d_ws, size_t ws_size,
                              hipStream_t stream) {
  const float* hs  = (const float*)d_in[0];
  const float* Wq  = (const float*)d_in[1];
  const float* bq  = (const float*)d_in[2];
  const float* Wk  = (const float*)d_in[3];
  const float* bk  = (const float*)d_in[4];
  const float* Wv  = (const float*)d_in[5];
  const float* bv  = (const float*)d_in[6];
  const float* Wqg = (const float*)d_in[7];
  const float* bqg = (const float*)d_in[8];
  const float* Wkg = (const float*)d_in[9];
  const float* bkg = (const float*)d_in[10];
  const float* Wvg = (const float*)d_in[11];
  const float* bvg = (const float*)d_in[12];
  float* out = (float*)d_out;

  char* ws = (char*)d_ws;
  const size_t bufB = (size_t)Bc * Sc * Dmc * sizeof(short);   // 12.58 MB
  short* qb = (short*)(ws);
  short* kb = (short*)(ws + bufB);
  short* vb = (short*)(ws + 2 * bufB);
  float* qg = (float*)(ws + 3 * bufB);                          // 98 KB
  float* pml = (float*)(ws + 3 * bufB + (1 << 20));             // 48 KB
  float* po  = (float*)(ws + 3 * bufB + (2 << 20));             // 1.57 MB

  dim3 gg(Bc * Sc / 64, Dmc / 64), bb(256);
  proj_gemm<<<gg, bb, 0, stream>>>(hs, Wq, bq, qb, SCALEc);
  proj_gemm<<<gg, bb, 0, stream>>>(hs, Wk, bk, kb, 1.0f);
  proj_gemm<<<gg, bb, 0, stream>>>(hs, Wv, bv, vb, 1.0f);
  qg_proj<<<dim3(Bc * Gc, Dmc / 256), bb, 0, stream>>>(hs, Wqg, bqg, qg);

  local_attn_mfma<<<dim3(Sc / 64, Hc, Bc), bb, 0, stream>>>(qb, kb, vb, out);

  // reuse q/k buffers for the global-path projections
  proj_gemm<<<gg, bb, 0, stream>>>(hs, Wkg, bkg, qb, 1.0f);
  proj_gemm<<<gg, bb, 0, stream>>>(hs, Wvg, bvg, kb, 1.0f);
  global_attn_part<<<dim3(Gc * NCH, Hc, Bc), bb, 0, stream>>>(qg, qb, kb, pml, po);
  global_attn_comb<<<dim3(Gc, Hc, Bc), dim3(64), 0, stream>>>(pml, po, out);
}

// Round 7
// 243.135 us; speedup vs baseline: 11.9287x; 1.5830x over previous
//
#include <hip/hip_runtime.h>

constexpr int Bc = 2, Sc = 4096, Dmc = 768, Hc = 12, HDc = 64, Wc = 256, Gc = 16;
constexpr int NCH = 16, CHK = 256;     // split-K for global rows
constexpr float SCALEc = 0.125f;   // 1/sqrt(64)
constexpr float NEGc = -10000.0f;

typedef __attribute__((ext_vector_type(8))) short s16x8;
typedef __attribute__((ext_vector_type(4))) short s16x4;
typedef __attribute__((ext_vector_type(4))) float f32x4;

#define DEVINL __device__ __forceinline__

DEVINL float b2f(short x) {
  unsigned int u = ((unsigned int)(unsigned short)x) << 16;
  return __builtin_bit_cast(float, u);
}
DEVINL short f2b(float f) {
  unsigned int u = __builtin_bit_cast(unsigned int, f);
  unsigned int r = (u + 0x7fffu + ((u >> 16) & 1u)) >> 16;
  return (short)r;
}

// ---------------- prep: f32 -> bf16 elementwise (hs), 8 elems/thread ----------------
__global__ __launch_bounds__(256) void conv_bf16(
    const float* __restrict__ src, short* __restrict__ dst)
{
  const size_t i = ((size_t)blockIdx.x * 256 + threadIdx.x) * 8;
  f32x4 a = *(const f32x4*)(src + i);
  f32x4 c = *(const f32x4*)(src + i + 4);
  s16x8 r;
#pragma unroll
  for (int u = 0; u < 4; ++u) { r[u] = f2b(a[u]); r[4 + u] = f2b(c[u]); }
  *(s16x8*)(dst + i) = r;
}

// ---------------- prep: W[k][n] f32 -> Wt[n][k] bf16 (32x32 LDS tile); z selects ----
__global__ __launch_bounds__(256) void transpose_w(
    const float* __restrict__ W0, const float* __restrict__ W1, const float* __restrict__ W2,
    short* __restrict__ T0, short* __restrict__ T1, short* __restrict__ T2)
{
  const float* W = blockIdx.z == 0 ? W0 : (blockIdx.z == 1 ? W1 : W2);
  short* T = blockIdx.z == 0 ? T0 : (blockIdx.z == 1 ? T1 : T2);
  __shared__ short t[32][33];
  const int k0 = blockIdx.x * 32, n0 = blockIdx.y * 32;
  const int a = threadIdx.x >> 3, cg = (threadIdx.x & 7) * 4;
  f32x4 v = *(const f32x4*)&W[(size_t)(k0 + a) * Dmc + n0 + cg];
#pragma unroll
  for (int u = 0; u < 4; ++u) t[a][cg + u] = f2b(v[u]);
  __syncthreads();
  s16x4 s;
#pragma unroll
  for (int u = 0; u < 4; ++u) s[u] = t[cg + u][a];
  *(s16x4*)&T[(size_t)(n0 + a) * Dmc + k0 + cg] = s;
}

// ---------------- projection GEMM (bf16 in): Y = (X @ Wt^T + b)*scale -> bf16 -------
// X: [8192][768] bf16 row-major; Wt: [n][k] bf16. BM=128, BN=64, BK=64, 4 waves.
// LDS XOR-swizzled: byte ^= ((row&7)<<4) within each 128B row.
__global__ __launch_bounds__(256) void gemm_bf16t(
    const short* __restrict__ X, const short* __restrict__ Wt,
    const float* __restrict__ bias, short* __restrict__ Y, float scale)
{
  __shared__ short lds[12288];    // A bytes [0,16384), B bytes [16384,24576)
  char* ldsb = (char*)lds;
  const int tid = threadIdx.x, lane = tid & 63, wid = tid >> 6;
  const int m0 = blockIdx.x * 128, n0 = blockIdx.y * 64;
  const int lr = lane & 15, lq = lane >> 4;
  const int wm = (wid & 1) * 64, wn = (wid >> 1) * 32;

  // staging: thread covers row (it*32 + tid>>3), byte col (tid&7)*16
  const int arow = tid >> 3, acol16 = (tid & 7) * 16;
  int awb[4], bwb[2];
#pragma unroll
  for (int it = 0; it < 4; ++it) {
    int row = it * 32 + arow;
    awb[it] = row * 128 + (acol16 ^ ((row & 7) << 4));
  }
#pragma unroll
  for (int it = 0; it < 2; ++it) {
    int row = it * 32 + arow;
    bwb[it] = 16384 + row * 128 + (acol16 ^ ((row & 7) << 4));
  }
  // frag read offsets
  int arb[4][2], brb[2][2];
#pragma unroll
  for (int mi = 0; mi < 4; ++mi)
#pragma unroll
    for (int ks = 0; ks < 2; ++ks) {
      int row = wm + mi * 16 + lr;
      arb[mi][ks] = row * 128 + ((lq * 16 + ks * 64) ^ ((row & 7) << 4));
    }
#pragma unroll
  for (int ni = 0; ni < 2; ++ni)
#pragma unroll
    for (int ks = 0; ks < 2; ++ks) {
      int row = wn + ni * 16 + lr;
      brb[ni][ks] = 16384 + row * 128 + ((lq * 16 + ks * 64) ^ ((row & 7) << 4));
    }

  const short* Abase = X + (size_t)m0 * Dmc + (acol16 >> 1);
  const short* Bbase = Wt + (size_t)n0 * Dmc + (acol16 >> 1);

  f32x4 acc[4][2] = {};

  for (int kt = 0; kt < 12; ++kt) {
    const int ko = kt * 64;
    s16x8 a0 = *(const s16x8*)(Abase + (size_t)(arow)       * Dmc + ko);
    s16x8 a1 = *(const s16x8*)(Abase + (size_t)(32 + arow)  * Dmc + ko);
    s16x8 a2 = *(const s16x8*)(Abase + (size_t)(64 + arow)  * Dmc + ko);
    s16x8 a3 = *(const s16x8*)(Abase + (size_t)(96 + arow)  * Dmc + ko);
    s16x8 b0 = *(const s16x8*)(Bbase + (size_t)(arow)       * Dmc + ko);
    s16x8 b1 = *(const s16x8*)(Bbase + (size_t)(32 + arow)  * Dmc + ko);
    __syncthreads();               // previous tile fully consumed
    *(s16x8*)(ldsb + awb[0]) = a0;
    *(s16x8*)(ldsb + awb[1]) = a1;
    *(s16x8*)(ldsb + awb[2]) = a2;
    *(s16x8*)(ldsb + awb[3]) = a3;
    *(s16x8*)(ldsb + bwb[0]) = b0;
    *(s16x8*)(ldsb + bwb[1]) = b1;
    __syncthreads();
#pragma unroll
    for (int ks = 0; ks < 2; ++ks) {
      s16x8 af[4], bf[2];
#pragma unroll
      for (int mi = 0; mi < 4; ++mi) af[mi] = *(const s16x8*)(ldsb + arb[mi][ks]);
#pragma unroll
      for (int ni = 0; ni < 2; ++ni) bf[ni] = *(const s16x8*)(ldsb + brb[ni][ks]);
#pragma unroll
      for (int mi = 0; mi < 4; ++mi)
#pragma unroll
        for (int ni = 0; ni < 2; ++ni)
          acc[mi][ni] = __builtin_amdgcn_mfma_f32_16x16x32_bf16(af[mi], bf[ni], acc[mi][ni], 0, 0, 0);
    }
  }

#pragma unroll
  for (int mi = 0; mi < 4; ++mi)
#pragma unroll
    for (int ni = 0; ni < 2; ++ni) {
      int col = n0 + wn + ni * 16 + lr;
      float bv_ = bias[col];
#pragma unroll
      for (int r = 0; r < 4; ++r) {
        int row = m0 + wm + mi * 16 + lq * 4 + r;
        Y[(size_t)row * Dmc + col] = f2b((acc[mi][ni][r] + bv_) * scale);
      }
    }
}

// ---------------- qg projection: grid (32, 6), 128 n x 2 c-halves ----------------
__global__ __launch_bounds__(256) void qg_proj(
    const float* __restrict__ hs, const float* __restrict__ Wqg,
    const float* __restrict__ bqg, float* __restrict__ qg)
{
  const int row = blockIdx.x;           // b*G + i
  const int b = row / Gc, i = row % Gc;
  const int tid = threadIdx.x;
  const int n = blockIdx.y * 128 + (tid & 127);
  const int half = tid >> 7;
  __shared__ float x[Dmc];
  __shared__ float part[128];
  for (int c = tid; c < Dmc; c += 256)
    x[c] = b2f(f2b(hs[((size_t)(b * Sc + i)) * Dmc + c]));
  __syncthreads();
  float acc = 0.f;
#pragma unroll 4
  for (int c = half * 384; c < half * 384 + 384; ++c)
    acc = fmaf(x[c], b2f(f2b(Wqg[(size_t)c * Dmc + n])), acc);
  if (half) part[tid & 127] = acc;
  __syncthreads();
  if (!half)
    qg[(size_t)row * Dmc + n] = (acc + part[tid] + bqg[n]) * SCALEc;
}

// ---------------- MFMA banded attention (unchanged from round 5) ----------------
__global__ __launch_bounds__(256) void local_attn_mfma(
    const short* __restrict__ q, const short* __restrict__ k,
    const short* __restrict__ v, float* __restrict__ out)
{
  const int q0 = blockIdx.x * 64;
  const int h = blockIdx.y, b = blockIdx.z;
  const int tid = threadIdx.x, lane = tid & 63, wid = tid >> 6;

  __shared__ short Ks[2048];
  __shared__ short Vt[2048];
  __shared__ short Ps[4][512];

  const int ql = lane & 15;
  const int lg = lane >> 4;
  const int qr = wid * 16 + ql;

  s16x8 qf[2];
  {
    const short* qp = q + ((size_t)(b * Sc + q0 + qr)) * Dmc + h * HDc + lg * 8;
    qf[0] = *(const s16x8*)qp;
    qf[1] = *(const s16x8*)(qp + 32);
  }

  f32x4 oacc[4] = {};
  float m_run = -INFINITY, l_run = 0.f;

  const int skr = tid >> 3;
  const int sdb = (tid & 7) * 8;

  for (int ch = 0; ch < 19; ++ch) {
    {
      int col = ch * 32 + skr;
      int key = (col < Gc) ? col : q0 - Wc + (col - Gc);
      int kc = min(max(key, 0), Sc - 1);
      const size_t rb = ((size_t)(b * Sc + kc)) * Dmc + h * HDc + sdb;
      s16x8 kv = *(const s16x8*)(k + rb);
      s16x8 vv = *(const s16x8*)(v + rb);
      int kbyte = (skr * 128 + sdb * 2) ^ ((skr & 7) << 4);
      *(s16x8*)((char*)Ks + kbyte) = kv;
#pragma unroll
      for (int j = 0; j < 8; ++j) {
        int d = sdb + j;
        int vbyte = (d * 64 + skr * 2) ^ ((d & 3) << 4);
        *(short*)((char*)Vt + vbyte) = vv[j];
      }
    }
    __syncthreads();

    f32x4 sac[2] = {};
#pragma unroll
    for (int kt = 0; kt < 2; ++kt) {
      int row = kt * 16 + ql;
#pragma unroll
      for (int sl = 0; sl < 2; ++sl) {
        int byte_ = (row * 128 + (lg * 8 + sl * 32) * 2) ^ ((row & 7) << 4);
        s16x8 af = *(const s16x8*)((const char*)Ks + byte_);
        sac[kt] = __builtin_amdgcn_mfma_f32_16x16x32_bf16(af, qf[sl], sac[kt], 0, 0, 0);
      }
    }

#pragma unroll
    for (int kt = 0; kt < 2; ++kt)
#pragma unroll
      for (int r = 0; r < 4; ++r) {
        int c = ch * 32 + kt * 16 + lg * 4 + r;
        if (c >= Gc) {
          float sv = sac[kt][r];
          int jj = c - Gc - qr;
          int kp2 = q0 - Wc + (c - Gc);
          bool ok = (jj >= 0) & (jj <= 2 * Wc) & (kp2 >= 0) & (kp2 < Sc);
          sac[kt][r] = ok ? (sv + ((kp2 < Gc) ? NEGc : 0.f)) : -INFINITY;
        }
      }

    float cm = -INFINITY;
#pragma unroll
    for (int kt = 0; kt < 2; ++kt)
#pragma unroll
      for (int r = 0; r < 4; ++r) cm = fmaxf(cm, sac[kt][r]);
    cm = fmaxf(cm, __shfl_xor(cm, 16));
    cm = fmaxf(cm, __shfl_xor(cm, 32));
    float m_new = fmaxf(m_run, cm);
    float scale = __expf(m_run - m_new);
    float cl = 0.f;
#pragma unroll
    for (int kt = 0; kt < 2; ++kt)
#pragma unroll
      for (int r = 0; r < 4; ++r) {
        float p = __expf(sac[kt][r] - m_new);
        sac[kt][r] = p;
        cl += p;
      }
    cl += __shfl_xor(cl, 16);
    cl += __shfl_xor(cl, 32);
    l_run = l_run * scale + cl;
    m_run = m_new;

#pragma unroll
    for (int rr = 0; rr < 4; ++rr) {
      float os = __shfl(scale, lg * 4 + rr);
#pragma unroll
      for (int dt = 0; dt < 4; ++dt) oacc[dt][rr] *= os;
    }

#pragma unroll
    for (int kt = 0; kt < 2; ++kt)
#pragma unroll
      for (int r = 0; r < 4; ++r) {
        int kk = kt * 16 + lg * 4 + r;
        int byte_ = (ql * 64 + kk * 2) ^ ((ql & 3) << 4);
        *(short*)((char*)Ps[wid] + byte_) = f2b(sac[kt][r]);
      }
    {
      int pbyte = (ql * 64 + lg * 16) ^ ((ql & 3) << 4);
      s16x8 pf = *(const s16x8*)((const char*)Ps[wid] + pbyte);
#pragma unroll
      for (int dt = 0; dt < 4; ++dt) {
        int d = dt * 16 + ql;
        int vbyte = (d * 64 + lg * 16) ^ ((d & 3) << 4);
        s16x8 vf = *(const s16x8*)((const char*)Vt + vbyte);
        oacc[dt] = __builtin_amdgcn_mfma_f32_16x16x32_bf16(pf, vf, oacc[dt], 0, 0, 0);
      }
    }
    __syncthreads();
  }

  float inv = 1.f / l_run;
#pragma unroll
  for (int rr = 0; rr < 4; ++rr) {
    float oi = __shfl(inv, lg * 4 + rr);
    int row = q0 + wid * 16 + lg * 4 + rr;
    float* op = out + ((size_t)(b * Sc + row)) * Dmc + h * HDc + ql;
#pragma unroll
    for (int dt = 0; dt < 4; ++dt)
      op[dt * 16] = oacc[dt][rr] * oi;
  }
}

// ---------------- global rows, split-K phase A (vectorized PV) ----------------
__global__ __launch_bounds__(256) void global_attn_part(
    const float* __restrict__ qg, const short* __restrict__ kg,
    const short* __restrict__ vg, float* __restrict__ pml, float* __restrict__ po)
{
  const int ch = blockIdx.x & (NCH - 1);
  const int i  = blockIdx.x >> 4;
  const int h = blockIdx.y, b = blockIdx.z;
  const int tid = threadIdx.x, lane = tid & 63, wid = tid >> 6;

  __shared__ float qrow[64];
  __shared__ float pls[CHK];
  __shared__ float red[8];
  __shared__ float osum[4][64];

  if (tid < 64) qrow[tid] = qg[(size_t)(b * Gc + i) * Dmc + h * HDc + tid];
  __syncthreads();

  const int sk = ch * CHK + tid;
  const s16x8* kr = (const s16x8*)(kg + ((size_t)(b * Sc + sk)) * Dmc + h * HDc);
  float acc = 0.f;
#pragma unroll
  for (int c = 0; c < 8; ++c) {
    s16x8 kv = kr[c];
#pragma unroll
    for (int u = 0; u < 8; ++u) acc = fmaf(qrow[c * 8 + u], b2f(kv[u]), acc);
  }

  float m = acc;
#pragma unroll
  for (int off = 32; off > 0; off >>= 1) m = fmaxf(m, __shfl_xor(m, off));
  if (lane == 0) red[wid] = m;
  __syncthreads();
  m = fmaxf(fmaxf(red[0], red[1]), fmaxf(red[2], red[3]));

  float p = __expf(acc - m);
  pls[tid] = p;
  float ls = p;
#pragma unroll
  for (int off = 32; off > 0; off >>= 1) ls += __shfl_xor(ls, off);
  if (lane == 0) red[4 + wid] = ls;
  __syncthreads();
  const float l = red[4] + red[5] + red[6] + red[7];

  // PV: thread = (j-group of 8 keys) x (d-octet); vector V loads
  const int jg = tid >> 3, db = (tid & 7) * 8;
  float o[8] = {};
  const short* vb2 = vg + ((size_t)(b * Sc + ch * CHK + jg * 8)) * Dmc + h * HDc + db;
#pragma unroll
  for (int jj = 0; jj < 8; ++jj) {
    float pw = pls[jg * 8 + jj];
    s16x8 vv = *(const s16x8*)(vb2 + (size_t)jj * Dmc);
#pragma unroll
    for (int u = 0; u < 8; ++u) o[u] = fmaf(pw, b2f(vv[u]), o[u]);
  }
#pragma unroll
  for (int mk = 8; mk <= 32; mk <<= 1)
#pragma unroll
    for (int u = 0; u < 8; ++u) o[u] += __shfl_xor(o[u], mk);
  if ((lane & 56) == 0) {
#pragma unroll
    for (int u = 0; u < 8; ++u) osum[wid][(lane & 7) * 8 + u] = o[u];
  }
  __syncthreads();

  const size_t slot = (((size_t)(b * Hc + h) * Gc + i) * NCH + ch);
  if (tid < 64)
    po[slot * 64 + tid] = osum[0][tid] + osum[1][tid] + osum[2][tid] + osum[3][tid];
  if (tid == 0) { pml[slot * 2] = m; pml[slot * 2 + 1] = l; }
}

// ---------------- global rows, split-K phase B: combine ----------------
__global__ __launch_bounds__(64) void global_attn_comb(
    const float* __restrict__ pml, const float* __restrict__ po,
    float* __restrict__ out)
{
  const int i = blockIdx.x, h = blockIdx.y, b = blockIdx.z;
  const int d = threadIdx.x;
  const size_t base = ((size_t)(b * Hc + h) * Gc + i) * NCH;

  float m = -INFINITY;
#pragma unroll
  for (int ch = 0; ch < NCH; ++ch) m = fmaxf(m, pml[(base + ch) * 2]);
  float l = 0.f, o = 0.f;
#pragma unroll
  for (int ch = 0; ch < NCH; ++ch) {
    float wgt = __expf(pml[(base + ch) * 2] - m);
    l = fmaf(pml[(base + ch) * 2 + 1], wgt, l);
    o = fmaf(po[(base + ch) * 64 + d], wgt, o);
  }
  out[((size_t)(b * Sc + i)) * Dmc + h * HDc + d] = o / l;
}

extern "C" void kernel_launch(void* const* d_in, const int* in_sizes, int n_in,
                              void* d_out, int out_size, void* d_ws, size_t ws_size,
                              hipStream_t stream) {
  const float* hs  = (const float*)d_in[0];
  const float* Wq  = (const float*)d_in[1];
  const float* bq  = (const float*)d_in[2];
  const float* Wk  = (const float*)d_in[3];
  const float* bk  = (const float*)d_in[4];
  const float* Wv  = (const float*)d_in[5];
  const float* bv  = (const float*)d_in[6];
  const float* Wqg = (const float*)d_in[7];
  const float* bqg = (const float*)d_in[8];
  const float* Wkg = (const float*)d_in[9];
  const float* bkg = (const float*)d_in[10];
  const float* Wvg = (const float*)d_in[11];
  const float* bvg = (const float*)d_in[12];
  float* out = (float*)d_out;

  char* ws = (char*)d_ws;
  const size_t bufB = (size_t)Bc * Sc * Dmc * sizeof(short);   // 12,582,912
  short* hsb = (short*)(ws);
  short* s1  = (short*)(ws + bufB);        // q -> kg
  short* s2  = (short*)(ws + 2 * bufB);    // k -> vg
  short* s3  = (short*)(ws + 3 * bufB);    // v -> {qg,pml,po | Wt_kg,Wt_vg}
  // total ws use: 4 * 12.58 MB = 50.33 MB (proven-safe bound)

  // scratch inside d_out (free until local_attn writes it):
  short* wtA = (short*)d_out;              // Wt_q  (1.18 MB)
  short* wtB = wtA + (size_t)Dmc * Dmc;    // Wt_k
  short* wtC = wtB + (size_t)Dmc * Dmc;    // Wt_v
  // scratch inside s3 after local_attn (v dead):
  float* qg  = (float*)(ws + 3 * bufB);                         // 98,304 B
  float* pml = (float*)(ws + 3 * bufB + 98304);                 // 49,152 B
  float* po  = (float*)(ws + 3 * bufB + 147456);                // 1.57 MB
  short* wtD = (short*)(ws + 3 * bufB + (4u << 20));            // Wt_kg
  short* wtE = wtD + (size_t)Dmc * Dmc;                         // Wt_vg

  dim3 bb(256);
  conv_bf16<<<dim3(3072), bb, 0, stream>>>(hs, hsb);
  transpose_w<<<dim3(24, 24, 3), bb, 0, stream>>>(Wq, Wk, Wv, wtA, wtB, wtC);

  dim3 gg(Bc * Sc / 128, Dmc / 64);
  gemm_bf16t<<<gg, bb, 0, stream>>>(hsb, wtA, bq, s1, SCALEc);
  gemm_bf16t<<<gg, bb, 0, stream>>>(hsb, wtB, bk, s2, 1.0f);
  gemm_bf16t<<<gg, bb, 0, stream>>>(hsb, wtC, bv, s3, 1.0f);

  local_attn_mfma<<<dim3(Sc / 64, Hc, Bc), bb, 0, stream>>>(s1, s2, s3, out);

  transpose_w<<<dim3(24, 24, 2), bb, 0, stream>>>(Wkg, Wvg, Wvg, wtD, wtE, wtE);
  gemm_bf16t<<<gg, bb, 0, stream>>>(hsb, wtD, bkg, s1, 1.0f);
  gemm_bf16t<<<gg, bb, 0, stream>>>(hsb, wtE, bvg, s2, 1.0f);

  qg_proj<<<dim3(Bc * Gc, Dmc / 128), bb, 0, stream>>>(hs, Wqg, bqg, qg);
  global_attn_part<<<dim3(Gc * NCH, Hc, Bc), bb, 0, stream>>>(qg, s1, s2, pml, po);
  global_attn_comb<<<dim3(Gc, Hc, Bc), dim3(64), 0, stream>>>(pml, po, out);
}

// Round 8
// 217.442 us; speedup vs baseline: 13.3382x; 1.1182x over previous
//
#include <hip/hip_runtime.h>

constexpr int Bc = 2, Sc = 4096, Dmc = 768, Hc = 12, HDc = 64, Wc = 256, Gc = 16;
constexpr int NCH = 16, CHK = 256;     // split-K for global rows
constexpr float SCALEc = 0.125f;   // 1/sqrt(64)
constexpr float NEGc = -10000.0f;

typedef __attribute__((ext_vector_type(8))) short s16x8;
typedef __attribute__((ext_vector_type(4))) short s16x4;
typedef __attribute__((ext_vector_type(4))) float f32x4;

#define DEVINL __device__ __forceinline__

DEVINL float b2f(short x) {
  unsigned int u = ((unsigned int)(unsigned short)x) << 16;
  return __builtin_bit_cast(float, u);
}
DEVINL short f2b(float f) {
  unsigned int u = __builtin_bit_cast(unsigned int, f);
  unsigned int r = (u + 0x7fffu + ((u >> 16) & 1u)) >> 16;
  return (short)r;
}

// ---------------- prep: f32 -> bf16 elementwise (hs), 8 elems/thread ----------------
__global__ __launch_bounds__(256) void conv_bf16(
    const float* __restrict__ src, short* __restrict__ dst)
{
  const size_t i = ((size_t)blockIdx.x * 256 + threadIdx.x) * 8;
  f32x4 a = *(const f32x4*)(src + i);
  f32x4 c = *(const f32x4*)(src + i + 4);
  s16x8 r;
#pragma unroll
  for (int u = 0; u < 4; ++u) { r[u] = f2b(a[u]); r[4 + u] = f2b(c[u]); }
  *(s16x8*)(dst + i) = r;
}

// ---------------- prep: W[k][n] f32 -> Wt[n][k] bf16 (32x32 LDS tile); z selects ----
__global__ __launch_bounds__(256) void transpose_w(
    const float* __restrict__ W0, const float* __restrict__ W1, const float* __restrict__ W2,
    short* __restrict__ T0, short* __restrict__ T1, short* __restrict__ T2)
{
  const float* W = blockIdx.z == 0 ? W0 : (blockIdx.z == 1 ? W1 : W2);
  short* T = blockIdx.z == 0 ? T0 : (blockIdx.z == 1 ? T1 : T2);
  __shared__ short t[32][33];
  const int k0 = blockIdx.x * 32, n0 = blockIdx.y * 32;
  const int a = threadIdx.x >> 3, cg = (threadIdx.x & 7) * 4;
  f32x4 v = *(const f32x4*)&W[(size_t)(k0 + a) * Dmc + n0 + cg];
#pragma unroll
  for (int u = 0; u < 4; ++u) t[a][cg + u] = f2b(v[u]);
  __syncthreads();
  s16x4 s;
#pragma unroll
  for (int u = 0; u < 4; ++u) s[u] = t[cg + u][a];
  *(s16x4*)&T[(size_t)(n0 + a) * Dmc + k0 + cg] = s;
}

// ---------------- projection GEMM (bf16 in): Y = (X @ Wt^T + b)*scale -> bf16 -------
__global__ __launch_bounds__(256) void gemm_bf16t(
    const short* __restrict__ X, const short* __restrict__ Wt,
    const float* __restrict__ bias, short* __restrict__ Y, float scale)
{
  __shared__ short lds[12288];    // A bytes [0,16384), B bytes [16384,24576)
  char* ldsb = (char*)lds;
  const int tid = threadIdx.x, lane = tid & 63, wid = tid >> 6;
  const int m0 = blockIdx.x * 128, n0 = blockIdx.y * 64;
  const int lr = lane & 15, lq = lane >> 4;
  const int wm = (wid & 1) * 64, wn = (wid >> 1) * 32;

  const int arow = tid >> 3, acol16 = (tid & 7) * 16;
  int awb[4], bwb[2];
#pragma unroll
  for (int it = 0; it < 4; ++it) {
    int row = it * 32 + arow;
    awb[it] = row * 128 + (acol16 ^ ((row & 7) << 4));
  }
#pragma unroll
  for (int it = 0; it < 2; ++it) {
    int row = it * 32 + arow;
    bwb[it] = 16384 + row * 128 + (acol16 ^ ((row & 7) << 4));
  }
  int arb[4][2], brb[2][2];
#pragma unroll
  for (int mi = 0; mi < 4; ++mi)
#pragma unroll
    for (int ks = 0; ks < 2; ++ks) {
      int row = wm + mi * 16 + lr;
      arb[mi][ks] = row * 128 + ((lq * 16 + ks * 64) ^ ((row & 7) << 4));
    }
#pragma unroll
  for (int ni = 0; ni < 2; ++ni)
#pragma unroll
    for (int ks = 0; ks < 2; ++ks) {
      int row = wn + ni * 16 + lr;
      brb[ni][ks] = 16384 + row * 128 + ((lq * 16 + ks * 64) ^ ((row & 7) << 4));
    }

  const short* Abase = X + (size_t)m0 * Dmc + (acol16 >> 1);
  const short* Bbase = Wt + (size_t)n0 * Dmc + (acol16 >> 1);

  f32x4 acc[4][2] = {};

  for (int kt = 0; kt < 12; ++kt) {
    const int ko = kt * 64;
    s16x8 a0 = *(const s16x8*)(Abase + (size_t)(arow)       * Dmc + ko);
    s16x8 a1 = *(const s16x8*)(Abase + (size_t)(32 + arow)  * Dmc + ko);
    s16x8 a2 = *(const s16x8*)(Abase + (size_t)(64 + arow)  * Dmc + ko);
    s16x8 a3 = *(const s16x8*)(Abase + (size_t)(96 + arow)  * Dmc + ko);
    s16x8 b0 = *(const s16x8*)(Bbase + (size_t)(arow)       * Dmc + ko);
    s16x8 b1 = *(const s16x8*)(Bbase + (size_t)(32 + arow)  * Dmc + ko);
    __syncthreads();
    *(s16x8*)(ldsb + awb[0]) = a0;
    *(s16x8*)(ldsb + awb[1]) = a1;
    *(s16x8*)(ldsb + awb[2]) = a2;
    *(s16x8*)(ldsb + awb[3]) = a3;
    *(s16x8*)(ldsb + bwb[0]) = b0;
    *(s16x8*)(ldsb + bwb[1]) = b1;
    __syncthreads();
#pragma unroll
    for (int ks = 0; ks < 2; ++ks) {
      s16x8 af[4], bf[2];
#pragma unroll
      for (int mi = 0; mi < 4; ++mi) af[mi] = *(const s16x8*)(ldsb + arb[mi][ks]);
#pragma unroll
      for (int ni = 0; ni < 2; ++ni) bf[ni] = *(const s16x8*)(ldsb + brb[ni][ks]);
#pragma unroll
      for (int mi = 0; mi < 4; ++mi)
#pragma unroll
        for (int ni = 0; ni < 2; ++ni)
          acc[mi][ni] = __builtin_amdgcn_mfma_f32_16x16x32_bf16(af[mi], bf[ni], acc[mi][ni], 0, 0, 0);
    }
  }

#pragma unroll
  for (int mi = 0; mi < 4; ++mi)
#pragma unroll
    for (int ni = 0; ni < 2; ++ni) {
      int col = n0 + wn + ni * 16 + lr;
      float bv_ = bias[col];
#pragma unroll
      for (int r = 0; r < 4; ++r) {
        int row = m0 + wm + mi * 16 + lq * 4 + r;
        Y[(size_t)row * Dmc + col] = f2b((acc[mi][ni][r] + bv_) * scale);
      }
    }
}

// ---------------- qg projection: grid (32, 6), 128 n x 2 c-halves ----------------
__global__ __launch_bounds__(256) void qg_proj(
    const float* __restrict__ hs, const float* __restrict__ Wqg,
    const float* __restrict__ bqg, float* __restrict__ qg)
{
  const int row = blockIdx.x;           // b*G + i
  const int b = row / Gc, i = row % Gc;
  const int tid = threadIdx.x;
  const int n = blockIdx.y * 128 + (tid & 127);
  const int half = tid >> 7;
  __shared__ float x[Dmc];
  __shared__ float part[128];
  for (int c = tid; c < Dmc; c += 256)
    x[c] = b2f(f2b(hs[((size_t)(b * Sc + i)) * Dmc + c]));
  __syncthreads();
  float acc = 0.f;
#pragma unroll 4
  for (int c = half * 384; c < half * 384 + 384; ++c)
    acc = fmaf(x[c], b2f(f2b(Wqg[(size_t)c * Dmc + n])), acc);
  if (half) part[tid & 127] = acc;
  __syncthreads();
  if (!half)
    qg[(size_t)row * Dmc + n] = (acc + part[tid] + bqg[n]) * SCALEc;
}

// ---------------- MFMA banded attention v2: KVBLK=64, conflict-free LDS ----------------
// 640 cols = 10 chunks x 64: cols 0..15 = global keys; 16..591 window; rest dead.
__global__ __launch_bounds__(256) void local_attn_mfma(
    const short* __restrict__ q, const short* __restrict__ k,
    const short* __restrict__ v, float* __restrict__ out)
{
  const int q0 = blockIdx.x * 64;
  const int h = blockIdx.y, b = blockIdx.z;
  const int tid = threadIdx.x, lane = tid & 63, wid = tid >> 6;

  __shared__ short Ks[4096];      // [64 key][64 d], 128B rows, XOR-swizzled
  __shared__ short Vt[4096];      // [64 d][64 key], 128B rows, XOR-swizzled
  __shared__ short Ps[4][1024];   // per-wave [16 q][64 k], 128B rows, XOR-swizzled
  char* KsB = (char*)Ks;
  char* VtB = (char*)Vt;

  const int ql = lane & 15;
  const int lg = lane >> 4;
  const int qr = wid * 16 + ql;

  s16x8 qf[2];
  {
    const short* qp = q + ((size_t)(b * Sc + q0 + qr)) * Dmc + h * HDc + lg * 8;
    qf[0] = *(const s16x8*)qp;
    qf[1] = *(const s16x8*)(qp + 32);
  }

  f32x4 oacc[4] = {};
  float m_run = -INFINITY, l_run = 0.f;

  // staging thread mappings
  const int krow = tid >> 3, kcol16 = (tid & 7) * 16;       // K: row, byte-col
  const int vp = tid & 31, vo = tid >> 5;                   // V: key-pair, d-octet
  const size_t hoff = (size_t)h * HDc;
  const size_t brow = (size_t)b * Sc;

  // column -> key position (clamped for addressing; masking handles validity)
  auto keyof = [&](int c) {
    int key = (c < Gc) ? c : q0 - 272 + c;
    return min(max(key, 0), Sc - 1);
  };

  s16x8 kreg0, kreg1, vreg0, vreg1;
  auto loadRegs = [&](int ch) {
    kreg0 = *(const s16x8*)(k + (brow + keyof(ch * 64 + krow))      * Dmc + hoff + (kcol16 >> 1));
    kreg1 = *(const s16x8*)(k + (brow + keyof(ch * 64 + 32 + krow)) * Dmc + hoff + (kcol16 >> 1));
    vreg0 = *(const s16x8*)(v + (brow + keyof(ch * 64 + 2 * vp))     * Dmc + hoff + vo * 8);
    vreg1 = *(const s16x8*)(v + (brow + keyof(ch * 64 + 2 * vp + 1)) * Dmc + hoff + vo * 8);
  };

  loadRegs(0);

  for (int ch = 0; ch < 10; ++ch) {
    __syncthreads();   // previous compute done; LDS free
    // K rows
    *(s16x8*)(KsB + krow * 128        + (kcol16 ^ ((krow & 7) << 4))) = kreg0;
    *(s16x8*)(KsB + (krow + 32) * 128 + (kcol16 ^ ((krow & 7) << 4))) = kreg1;
    // V transposed: pair-packed b32 writes (conflict-free)
#pragma unroll
    for (int j = 0; j < 8; ++j) {
      int d = vo * 8 + j;
      unsigned int wrd = (unsigned int)(unsigned short)vreg0[j] |
                         ((unsigned int)(unsigned short)vreg1[j] << 16);
      *(unsigned int*)(VtB + d * 128 + ((4 * vp) ^ (j << 4))) = wrd;
    }
    if (ch < 9) loadRegs(ch + 1);   // prefetch next chunk under this chunk's compute
    __syncthreads();

    // ---- S^T tiles: D[k][q], 4 tiles of 16 keys ----
    f32x4 sac[4] = {};
#pragma unroll
    for (int kt = 0; kt < 4; ++kt) {
      int row = kt * 16 + ql;
#pragma unroll
      for (int sl = 0; sl < 2; ++sl) {
        s16x8 af = *(const s16x8*)(KsB + row * 128 + ((lg * 16 + sl * 64) ^ ((row & 7) << 4)));
        sac[kt] = __builtin_amdgcn_mfma_f32_16x16x32_bf16(af, qf[sl], sac[kt], 0, 0, 0);
      }
    }

    // ---- mask (skipped for interior chunks) ----
    bool needMask = (ch < 2) | (ch > 7) | (q0 < 272) | (q0 > Sc - 384);
    if (needMask) {
#pragma unroll
      for (int kt = 0; kt < 4; ++kt)
#pragma unroll
        for (int r = 0; r < 4; ++r) {
          int c = ch * 64 + kt * 16 + lg * 4 + r;
          if (c >= Gc) {
            float sv = sac[kt][r];
            int jj = c - Gc - qr;
            int kp2 = q0 - 272 + c;
            bool ok = (jj >= 0) & (jj <= 2 * Wc) & (kp2 >= 0) & (kp2 < Sc);
            sac[kt][r] = ok ? (sv + ((kp2 < Gc) ? NEGc : 0.f)) : -INFINITY;
          }
        }
    }

    // ---- online softmax (per-q stats at lane&15==q) ----
    float cm = -INFINITY;
#pragma unroll
    for (int kt = 0; kt < 4; ++kt)
#pragma unroll
      for (int r = 0; r < 4; ++r) cm = fmaxf(cm, sac[kt][r]);
    cm = fmaxf(cm, __shfl_xor(cm, 16));
    cm = fmaxf(cm, __shfl_xor(cm, 32));
    float m_new = fmaxf(m_run, cm);
    float scale = __expf(m_run - m_new);
    float cl = 0.f;
#pragma unroll
    for (int kt = 0; kt < 4; ++kt)
#pragma unroll
      for (int r = 0; r < 4; ++r) {
        float p = __expf(sac[kt][r] - m_new);
        sac[kt][r] = p;
        cl += p;
      }
    cl += __shfl_xor(cl, 16);
    cl += __shfl_xor(cl, 32);
    l_run = l_run * scale + cl;
    m_run = m_new;

    // rescale O
#pragma unroll
    for (int rr = 0; rr < 4; ++rr) {
      float os = __shfl(scale, lg * 4 + rr);
#pragma unroll
      for (int dt = 0; dt < 4; ++dt) oacc[dt][rr] *= os;
    }

    // ---- P -> bf16 into per-wave Ps [16][64] (b64 packed, 2-way max) ----
    char* PsB = (char*)Ps[wid];
#pragma unroll
    for (int kt = 0; kt < 4; ++kt) {
      s16x4 ps;
#pragma unroll
      for (int r = 0; r < 4; ++r) ps[r] = f2b(sac[kt][r]);
      *(s16x4*)(PsB + ql * 128 + ((kt * 32 + lg * 8) ^ ((ql & 7) << 4))) = ps;
    }
    // ---- PV: A=P fragments, B=V^T fragments, 2 k-halves ----
    s16x8 pf[2];
#pragma unroll
    for (int ks = 0; ks < 2; ++ks)
      pf[ks] = *(const s16x8*)(PsB + ql * 128 + ((ks * 64 + lg * 16) ^ ((ql & 7) << 4)));
#pragma unroll
    for (int dt = 0; dt < 4; ++dt) {
      int d = dt * 16 + ql;
#pragma unroll
      for (int ks = 0; ks < 2; ++ks) {
        s16x8 vf = *(const s16x8*)(VtB + d * 128 + ((ks * 64 + lg * 16) ^ ((d & 7) << 4)));
        oacc[dt] = __builtin_amdgcn_mfma_f32_16x16x32_bf16(pf[ks], vf, oacc[dt], 0, 0, 0);
      }
    }
  }

  float inv = 1.f / l_run;
#pragma unroll
  for (int rr = 0; rr < 4; ++rr) {
    float oi = __shfl(inv, lg * 4 + rr);
    int row = q0 + wid * 16 + lg * 4 + rr;
    float* op = out + ((size_t)(b * Sc + row)) * Dmc + h * HDc + ql;
#pragma unroll
    for (int dt = 0; dt < 4; ++dt)
      op[dt * 16] = oacc[dt][rr] * oi;
  }
}

// ---------------- global rows, split-K phase A (vectorized PV) ----------------
__global__ __launch_bounds__(256) void global_attn_part(
    const float* __restrict__ qg, const short* __restrict__ kg,
    const short* __restrict__ vg, float* __restrict__ pml, float* __restrict__ po)
{
  const int ch = blockIdx.x & (NCH - 1);
  const int i  = blockIdx.x >> 4;
  const int h = blockIdx.y, b = blockIdx.z;
  const int tid = threadIdx.x, lane = tid & 63, wid = tid >> 6;

  __shared__ float qrow[64];
  __shared__ float pls[CHK];
  __shared__ float red[8];
  __shared__ float osum[4][64];

  if (tid < 64) qrow[tid] = qg[(size_t)(b * Gc + i) * Dmc + h * HDc + tid];
  __syncthreads();

  const int sk = ch * CHK + tid;
  const s16x8* kr = (const s16x8*)(kg + ((size_t)(b * Sc + sk)) * Dmc + h * HDc);
  float acc = 0.f;
#pragma unroll
  for (int c = 0; c < 8; ++c) {
    s16x8 kv = kr[c];
#pragma unroll
    for (int u = 0; u < 8; ++u) acc = fmaf(qrow[c * 8 + u], b2f(kv[u]), acc);
  }

  float m = acc;
#pragma unroll
  for (int off = 32; off > 0; off >>= 1) m = fmaxf(m, __shfl_xor(m, off));
  if (lane == 0) red[wid] = m;
  __syncthreads();
  m = fmaxf(fmaxf(red[0], red[1]), fmaxf(red[2], red[3]));

  float p = __expf(acc - m);
  pls[tid] = p;
  float ls = p;
#pragma unroll
  for (int off = 32; off > 0; off >>= 1) ls += __shfl_xor(ls, off);
  if (lane == 0) red[4 + wid] = ls;
  __syncthreads();
  const float l = red[4] + red[5] + red[6] + red[7];

  const int jg = tid >> 3, db = (tid & 7) * 8;
  float o[8] = {};
  const short* vb2 = vg + ((size_t)(b * Sc + ch * CHK + jg * 8)) * Dmc + h * HDc + db;
#pragma unroll
  for (int jj = 0; jj < 8; ++jj) {
    float pw = pls[jg * 8 + jj];
    s16x8 vv = *(const s16x8*)(vb2 + (size_t)jj * Dmc);
#pragma unroll
    for (int u = 0; u < 8; ++u) o[u] = fmaf(pw, b2f(vv[u]), o[u]);
  }
#pragma unroll
  for (int mk = 8; mk <= 32; mk <<= 1)
#pragma unroll
    for (int u = 0; u < 8; ++u) o[u] += __shfl_xor(o[u], mk);
  if ((lane & 56) == 0) {
#pragma unroll
    for (int u = 0; u < 8; ++u) osum[wid][(lane & 7) * 8 + u] = o[u];
  }
  __syncthreads();

  const size_t slot = (((size_t)(b * Hc + h) * Gc + i) * NCH + ch);
  if (tid < 64)
    po[slot * 64 + tid] = osum[0][tid] + osum[1][tid] + osum[2][tid] + osum[3][tid];
  if (tid == 0) { pml[slot * 2] = m; pml[slot * 2 + 1] = l; }
}

// ---------------- global rows, split-K phase B: combine ----------------
__global__ __launch_bounds__(64) void global_attn_comb(
    const float* __restrict__ pml, const float* __restrict__ po,
    float* __restrict__ out)
{
  const int i = blockIdx.x, h = blockIdx.y, b = blockIdx.z;
  const int d = threadIdx.x;
  const size_t base = ((size_t)(b * Hc + h) * Gc + i) * NCH;

  float m = -INFINITY;
#pragma unroll
  for (int ch = 0; ch < NCH; ++ch) m = fmaxf(m, pml[(base + ch) * 2]);
  float l = 0.f, o = 0.f;
#pragma unroll
  for (int ch = 0; ch < NCH; ++ch) {
    float wgt = __expf(pml[(base + ch) * 2] - m);
    l = fmaf(pml[(base + ch) * 2 + 1], wgt, l);
    o = fmaf(po[(base + ch) * 64 + d], wgt, o);
  }
  out[((size_t)(b * Sc + i)) * Dmc + h * HDc + d] = o / l;
}

extern "C" void kernel_launch(void* const* d_in, const int* in_sizes, int n_in,
                              void* d_out, int out_size, void* d_ws, size_t ws_size,
                              hipStream_t stream) {
  const float* hs  = (const float*)d_in[0];
  const float* Wq  = (const float*)d_in[1];
  const float* bq  = (const float*)d_in[2];
  const float* Wk  = (const float*)d_in[3];
  const float* bk  = (const float*)d_in[4];
  const float* Wv  = (const float*)d_in[5];
  const float* bv  = (const float*)d_in[6];
  const float* Wqg = (const float*)d_in[7];
  const float* bqg = (const float*)d_in[8];
  const float* Wkg = (const float*)d_in[9];
  const float* bkg = (const float*)d_in[10];
  const float* Wvg = (const float*)d_in[11];
  const float* bvg = (const float*)d_in[12];
  float* out = (float*)d_out;

  char* ws = (char*)d_ws;
  const size_t bufB = (size_t)Bc * Sc * Dmc * sizeof(short);   // 12,582,912
  short* hsb = (short*)(ws);
  short* s1  = (short*)(ws + bufB);        // q -> kg
  short* s2  = (short*)(ws + 2 * bufB);    // k -> vg
  short* s3  = (short*)(ws + 3 * bufB);    // v -> {qg,pml,po | Wt_kg,Wt_vg}

  short* wtA = (short*)d_out;              // Wt_q (d_out free until local_attn)
  short* wtB = wtA + (size_t)Dmc * Dmc;    // Wt_k
  short* wtC = wtB + (size_t)Dmc * Dmc;    // Wt_v
  float* qg  = (float*)(ws + 3 * bufB);
  float* pml = (float*)(ws + 3 * bufB + 98304);
  float* po  = (float*)(ws + 3 * bufB + 147456);
  short* wtD = (short*)(ws + 3 * bufB + (4u << 20));            // Wt_kg
  short* wtE = wtD + (size_t)Dmc * Dmc;                         // Wt_vg

  dim3 bb(256);
  conv_bf16<<<dim3(3072), bb, 0, stream>>>(hs, hsb);
  transpose_w<<<dim3(24, 24, 3), bb, 0, stream>>>(Wq, Wk, Wv, wtA, wtB, wtC);

  dim3 gg(Bc * Sc / 128, Dmc / 64);
  gemm_bf16t<<<gg, bb, 0, stream>>>(hsb, wtA, bq, s1, SCALEc);
  gemm_bf16t<<<gg, bb, 0, stream>>>(hsb, wtB, bk, s2, 1.0f);
  gemm_bf16t<<<gg, bb, 0, stream>>>(hsb, wtC, bv, s3, 1.0f);

  local_attn_mfma<<<dim3(Sc / 64, Hc, Bc), bb, 0, stream>>>(s1, s2, s3, out);

  transpose_w<<<dim3(24, 24, 2), bb, 0, stream>>>(Wkg, Wvg, Wvg, wtD, wtE, wtE);
  gemm_bf16t<<<gg, bb, 0, stream>>>(hsb, wtD, bkg, s1, 1.0f);
  gemm_bf16t<<<gg, bb, 0, stream>>>(hsb, wtE, bvg, s2, 1.0f);

  qg_proj<<<dim3(Bc * Gc, Dmc / 128), bb, 0, stream>>>(hs, Wqg, bqg, qg);
  global_attn_part<<<dim3(Gc * NCH, Hc, Bc), bb, 0, stream>>>(qg, s1, s2, pml, po);
  global_attn_comb<<<dim3(Gc, Hc, Bc), dim3(64), 0, stream>>>(pml, po, out);
}

// Round 9
// 200.217 us; speedup vs baseline: 14.4858x; 1.0860x over previous
//
#include <hip/hip_runtime.h>

constexpr int Bc = 2, Sc = 4096, Dmc = 768, Hc = 12, HDc = 64, Wc = 256, Gc = 16;
constexpr int NCH = 16, CHK = 256;     // split-K for global rows
constexpr float LOG2E = 1.4426950408889634f;
constexpr float SCALEc = 0.125f;
constexpr float SCALE2q = 0.125f * LOG2E;   // q-scale in exp2 domain
constexpr float NEG2c = -10000.0f * LOG2E;  // mask addend in exp2 domain

typedef __attribute__((ext_vector_type(8))) short s16x8;
typedef __attribute__((ext_vector_type(4))) short s16x4;
typedef __attribute__((ext_vector_type(4))) float f32x4;
typedef __attribute__((ext_vector_type(2))) unsigned int u32x2;

#define DEVINL __device__ __forceinline__

DEVINL float b2f(short x) {
  unsigned int u = ((unsigned int)(unsigned short)x) << 16;
  return __builtin_bit_cast(float, u);
}
DEVINL short f2b(float f) {
  unsigned int u = __builtin_bit_cast(unsigned int, f);
  unsigned int r = (u + 0x7fffu + ((u >> 16) & 1u)) >> 16;
  return (short)r;
}
DEVINL void gload16(const short* g, const short* l) {
  __builtin_amdgcn_global_load_lds(
      (const __attribute__((address_space(1))) void*)g,
      (__attribute__((address_space(3))) void*)l, 16, 0, 0);
}

// ---------------- prep: f32 -> bf16 elementwise ----------------
__global__ __launch_bounds__(256) void conv_bf16(
    const float* __restrict__ src, short* __restrict__ dst)
{
  const size_t i = ((size_t)blockIdx.x * 256 + threadIdx.x) * 8;
  f32x4 a = *(const f32x4*)(src + i);
  f32x4 c = *(const f32x4*)(src + i + 4);
  s16x8 r;
#pragma unroll
  for (int u = 0; u < 4; ++u) { r[u] = f2b(a[u]); r[4 + u] = f2b(c[u]); }
  *(s16x8*)(dst + i) = r;
}

// ---------------- prep: W[k][n] f32 -> Wt[n][k] bf16 ----------------
__global__ __launch_bounds__(256) void transpose_w(
    const float* __restrict__ W0, const float* __restrict__ W1, const float* __restrict__ W2,
    short* __restrict__ T0, short* __restrict__ T1, short* __restrict__ T2)
{
  const float* W = blockIdx.z == 0 ? W0 : (blockIdx.z == 1 ? W1 : W2);
  short* T = blockIdx.z == 0 ? T0 : (blockIdx.z == 1 ? T1 : T2);
  __shared__ short t[32][33];
  const int k0 = blockIdx.x * 32, n0 = blockIdx.y * 32;
  const int a = threadIdx.x >> 3, cg = (threadIdx.x & 7) * 4;
  f32x4 v = *(const f32x4*)&W[(size_t)(k0 + a) * Dmc + n0 + cg];
#pragma unroll
  for (int u = 0; u < 4; ++u) t[a][cg + u] = f2b(v[u]);
  __syncthreads();
  s16x4 s;
#pragma unroll
  for (int u = 0; u < 4; ++u) s[u] = t[cg + u][a];
  *(s16x4*)&T[(size_t)(n0 + a) * Dmc + k0 + cg] = s;
}

// ---------------- merged projection GEMM via global_load_lds -----------------
// X:[8192][768] bf16; Wt:[gy*64][768] bf16 (concatenated). BM=128,BN=64,BK=64.
// Linear LDS dest + pre-swizzled global src + swizzled ds_read (involution).
// Output chunk nch = n/768 -> Y0 + nch*6291456, bias/scale selected per chunk.
__global__ __launch_bounds__(256) void gemm_fused(
    const short* __restrict__ X, const short* __restrict__ Wt,
    const float* __restrict__ b0, const float* __restrict__ b1, const float* __restrict__ b2,
    short* __restrict__ Y0, float scale0)
{
  __shared__ short lds[24576];   // 2 bufs x (A 8192 + B 4096 shorts)
  char* ldsb = (char*)lds;
  const int tid = threadIdx.x, lane = tid & 63, wid = tid >> 6;
  const int gy = gridDim.y;

  // bijective XCD swizzle (nwg = 64*gy, divisible by 8)
  const int rawd = blockIdx.x + 64 * blockIdx.y;
  const int wgid = (rawd & 7) * (gy * 8) + (rawd >> 3);
  const int mi0 = wgid / gy, ny = wgid - mi0 * gy;
  const int m0 = mi0 * 128;
  const int nch = ny / 12, ncol = (ny % 12) * 64;
  const int n0g = ny * 64;

  short* Y = Y0 + (size_t)nch * 6291456;
  const float* bias = nch == 0 ? b0 : (nch == 1 ? b1 : b2);
  const float scale = nch == 0 ? scale0 : 1.0f;

  const int lr = lane & 15, lq = lane >> 4;
  const int wm = (wid & 1) * 64, wn = (wid >> 1) * 32;

  // staging source (pre-swizzled column)
  const int l8 = lane >> 3, l7 = lane & 7;
  const int colsh = ((l7 * 16) ^ (l8 << 4)) >> 1;     // shorts
  const short* Aptr[4];
  const short* Bptr[2];
#pragma unroll
  for (int i = 0; i < 4; ++i)
    Aptr[i] = X + (size_t)(m0 + wid * 32 + i * 8 + l8) * Dmc + colsh;
#pragma unroll
  for (int i = 0; i < 2; ++i)
    Bptr[i] = Wt + (size_t)(n0g + wid * 16 + i * 8 + l8) * Dmc + colsh;

  // frag read byte offsets (within one buffer)
  int arb[4][2], brb[2][2];
#pragma unroll
  for (int mi = 0; mi < 4; ++mi)
#pragma unroll
    for (int ks = 0; ks < 2; ++ks) {
      int row = wm + mi * 16 + lr;
      arb[mi][ks] = row * 128 + ((lq * 16 + ks * 64) ^ ((row & 7) << 4));
    }
#pragma unroll
  for (int ni = 0; ni < 2; ++ni)
#pragma unroll
    for (int ks = 0; ks < 2; ++ks) {
      int row = wn + ni * 16 + lr;
      brb[ni][ks] = 16384 + row * 128 + ((lq * 16 + ks * 64) ^ ((row & 7) << 4));
    }

  f32x4 acc[4][2] = {};

  auto issue = [&](int kt, int buf) {
    const int ko = kt * 64, bo = buf * 12288;
#pragma unroll
    for (int i = 0; i < 4; ++i) gload16(Aptr[i] + ko, &lds[bo + wid * 2048 + i * 512]);
#pragma unroll
    for (int i = 0; i < 2; ++i) gload16(Bptr[i] + ko, &lds[bo + 8192 + wid * 1024 + i * 512]);
  };

  issue(0, 0);
  for (int kt = 0; kt < 12; ++kt) {
    const int buf = kt & 1, bo = buf * 24576;
    asm volatile("s_waitcnt vmcnt(0)" ::: "memory");
    __syncthreads();
    if (kt < 11) issue(kt + 1, buf ^ 1);
#pragma unroll
    for (int ks = 0; ks < 2; ++ks) {
      s16x8 af[4], bf[2];
#pragma unroll
      for (int mi = 0; mi < 4; ++mi) af[mi] = *(const s16x8*)(ldsb + bo + arb[mi][ks]);
#pragma unroll
      for (int ni = 0; ni < 2; ++ni) bf[ni] = *(const s16x8*)(ldsb + bo + brb[ni][ks]);
#pragma unroll
      for (int mi = 0; mi < 4; ++mi)
#pragma unroll
        for (int ni = 0; ni < 2; ++ni)
          acc[mi][ni] = __builtin_amdgcn_mfma_f32_16x16x32_bf16(af[mi], bf[ni], acc[mi][ni], 0, 0, 0);
    }
  }

#pragma unroll
  for (int mi = 0; mi < 4; ++mi)
#pragma unroll
    for (int ni = 0; ni < 2; ++ni) {
      int col = ncol + wn + ni * 16 + lr;
      float bv_ = bias[col];
#pragma unroll
      for (int r = 0; r < 4; ++r) {
        int row = m0 + wm + mi * 16 + lq * 4 + r;
        Y[(size_t)row * Dmc + col] = f2b((acc[mi][ni][r] + bv_) * scale);
      }
    }
}

// ---------------- qg projection (exp2-domain scale) ----------------
__global__ __launch_bounds__(256) void qg_proj(
    const float* __restrict__ hs, const float* __restrict__ Wqg,
    const float* __restrict__ bqg, float* __restrict__ qg)
{
  const int row = blockIdx.x;
  const int b = row / Gc, i = row % Gc;
  const int tid = threadIdx.x;
  const int n = blockIdx.y * 128 + (tid & 127);
  const int half = tid >> 7;
  __shared__ float x[Dmc];
  __shared__ float part[128];
  for (int c = tid; c < Dmc; c += 256)
    x[c] = b2f(f2b(hs[((size_t)(b * Sc + i)) * Dmc + c]));
  __syncthreads();
  float acc = 0.f;
#pragma unroll 4
  for (int c = half * 384; c < half * 384 + 384; ++c)
    acc = fmaf(x[c], b2f(f2b(Wqg[(size_t)c * Dmc + n])), acc);
  if (half) part[tid & 127] = acc;
  __syncthreads();
  if (!half)
    qg[(size_t)row * Dmc + n] = (acc + part[tid] + bqg[n]) * SCALE2q;
}

// ---------------- MFMA banded attention v3: exp2, cvt_pk, defer-max, XCD swz ----
__global__ __launch_bounds__(256) void local_attn_mfma(
    const short* __restrict__ q, const short* __restrict__ k,
    const short* __restrict__ v, float* __restrict__ out)
{
  // XCD swizzle: adjacent q0 blocks share 87% of K/V window -> same XCD L2
  const int raw = blockIdx.x + 64 * (blockIdx.y + 12 * blockIdx.z);
  const int swz = (raw & 7) * 192 + (raw >> 3);
  const int q0 = (swz & 63) * 64;
  const int h = (swz >> 6) % 12, b = swz / 768;
  const int tid = threadIdx.x, lane = tid & 63, wid = tid >> 6;

  __shared__ short Ks[4096];
  __shared__ short Vt[4096];
  __shared__ short Ps[4][1024];
  char* KsB = (char*)Ks;
  char* VtB = (char*)Vt;

  const int ql = lane & 15;
  const int lg = lane >> 4;
  const int qr = wid * 16 + ql;

  s16x8 qf[2];
  {
    const short* qp = q + ((size_t)(b * Sc + q0 + qr)) * Dmc + h * HDc + lg * 8;
    qf[0] = *(const s16x8*)qp;
    qf[1] = *(const s16x8*)(qp + 32);
  }

  f32x4 oacc[4] = {};
  float m_run = -INFINITY, l_run = 0.f;

  const int krow = tid >> 3, kcol16 = (tid & 7) * 16;
  const int vp = tid & 31, vo = tid >> 5;
  const size_t hoff = (size_t)h * HDc;
  const size_t brow = (size_t)b * Sc;

  auto keyof = [&](int c) {
    int key = (c < Gc) ? c : q0 - 272 + c;
    return min(max(key, 0), Sc - 1);
  };

  s16x8 kreg0, kreg1, vreg0, vreg1;
  auto loadRegs = [&](int ch) {
    kreg0 = *(const s16x8*)(k + (brow + keyof(ch * 64 + krow))      * Dmc + hoff + (kcol16 >> 1));
    kreg1 = *(const s16x8*)(k + (brow + keyof(ch * 64 + 32 + krow)) * Dmc + hoff + (kcol16 >> 1));
    vreg0 = *(const s16x8*)(v + (brow + keyof(ch * 64 + 2 * vp))     * Dmc + hoff + vo * 8);
    vreg1 = *(const s16x8*)(v + (brow + keyof(ch * 64 + 2 * vp + 1)) * Dmc + hoff + vo * 8);
  };

  loadRegs(0);

  for (int ch = 0; ch < 10; ++ch) {
    __syncthreads();
    *(s16x8*)(KsB + krow * 128        + (kcol16 ^ ((krow & 7) << 4))) = kreg0;
    *(s16x8*)(KsB + (krow + 32) * 128 + (kcol16 ^ ((krow & 7) << 4))) = kreg1;
#pragma unroll
    for (int j = 0; j < 8; ++j) {
      int d = vo * 8 + j;
      unsigned int wrd = (unsigned int)(unsigned short)vreg0[j] |
                         ((unsigned int)(unsigned short)vreg1[j] << 16);
      *(unsigned int*)(VtB + d * 128 + ((4 * vp) ^ (j << 4))) = wrd;
    }
    if (ch < 9) loadRegs(ch + 1);
    __syncthreads();

    f32x4 sac[4] = {};
#pragma unroll
    for (int kt = 0; kt < 4; ++kt) {
      int row = kt * 16 + ql;
#pragma unroll
      for (int sl = 0; sl < 2; ++sl) {
        s16x8 af = *(const s16x8*)(KsB + row * 128 + ((lg * 16 + sl * 64) ^ ((row & 7) << 4)));
        sac[kt] = __builtin_amdgcn_mfma_f32_16x16x32_bf16(af, qf[sl], sac[kt], 0, 0, 0);
      }
    }

    bool needMask = (ch < 2) | (ch > 7) | (q0 < 272) | (q0 > Sc - 384);
    if (needMask) {
#pragma unroll
      for (int kt = 0; kt < 4; ++kt)
#pragma unroll
        for (int r = 0; r < 4; ++r) {
          int c = ch * 64 + kt * 16 + lg * 4 + r;
          if (c >= Gc) {
            float sv = sac[kt][r];
            int jj = c - Gc - qr;
            int kp2 = q0 - 272 + c;
            bool ok = (jj >= 0) & (jj <= 2 * Wc) & (kp2 >= 0) & (kp2 < Sc);
            sac[kt][r] = ok ? (sv + ((kp2 < Gc) ? NEG2c : 0.f)) : -INFINITY;
          }
        }
    }

    float cm = -INFINITY;
#pragma unroll
    for (int kt = 0; kt < 4; ++kt)
#pragma unroll
      for (int r = 0; r < 4; ++r) cm = fmaxf(cm, sac[kt][r]);
    cm = fmaxf(cm, __shfl_xor(cm, 16));
    cm = fmaxf(cm, __shfl_xor(cm, 32));

    if (__all(cm <= m_run + 11.5f)) {
      // defer-max: keep m_run, skip O-rescale (P bounded by 2^11.5)
      float cl = 0.f;
#pragma unroll
      for (int kt = 0; kt < 4; ++kt)
#pragma unroll
        for (int r = 0; r < 4; ++r) {
          float p = exp2f(sac[kt][r] - m_run);
          sac[kt][r] = p;
          cl += p;
        }
      cl += __shfl_xor(cl, 16);
      cl += __shfl_xor(cl, 32);
      l_run += cl;
    } else {
      float m_new = fmaxf(m_run, cm);
      float scale = exp2f(m_run - m_new);
      float cl = 0.f;
#pragma unroll
      for (int kt = 0; kt < 4; ++kt)
#pragma unroll
        for (int r = 0; r < 4; ++r) {
          float p = exp2f(sac[kt][r] - m_new);
          sac[kt][r] = p;
          cl += p;
        }
      cl += __shfl_xor(cl, 16);
      cl += __shfl_xor(cl, 32);
      l_run = l_run * scale + cl;
      m_run = m_new;
#pragma unroll
      for (int rr = 0; rr < 4; ++rr) {
        float os = __shfl(scale, lg * 4 + rr);
#pragma unroll
        for (int dt = 0; dt < 4; ++dt) oacc[dt][rr] *= os;
      }
    }

    // P -> bf16 via v_cvt_pk_bf16_f32 (8 ops for 16 values)
    char* PsB = (char*)Ps[wid];
#pragma unroll
    for (int kt = 0; kt < 4; ++kt) {
      u32x2 pw;
      asm("v_cvt_pk_bf16_f32 %0, %1, %2" : "=v"(pw.x) : "v"(sac[kt][0]), "v"(sac[kt][1]));
      asm("v_cvt_pk_bf16_f32 %0, %1, %2" : "=v"(pw.y) : "v"(sac[kt][2]), "v"(sac[kt][3]));
      *(u32x2*)(PsB + ql * 128 + ((kt * 32 + lg * 8) ^ ((ql & 7) << 4))) = pw;
    }
    s16x8 pf[2];
#pragma unroll
    for (int ks = 0; ks < 2; ++ks)
      pf[ks] = *(const s16x8*)(PsB + ql * 128 + ((ks * 64 + lg * 16) ^ ((ql & 7) << 4)));
#pragma unroll
    for (int dt = 0; dt < 4; ++dt) {
      int d = dt * 16 + ql;
#pragma unroll
      for (int ks = 0; ks < 2; ++ks) {
        s16x8 vf = *(const s16x8*)(VtB + d * 128 + ((ks * 64 + lg * 16) ^ ((d & 7) << 4)));
        oacc[dt] = __builtin_amdgcn_mfma_f32_16x16x32_bf16(pf[ks], vf, oacc[dt], 0, 0, 0);
      }
    }
  }

  float inv = 1.f / l_run;
#pragma unroll
  for (int rr = 0; rr < 4; ++rr) {
    float oi = __shfl(inv, lg * 4 + rr);
    int row = q0 + wid * 16 + lg * 4 + rr;
    float* op = out + ((size_t)(b * Sc + row)) * Dmc + h * HDc + ql;
#pragma unroll
    for (int dt = 0; dt < 4; ++dt)
      op[dt * 16] = oacc[dt][rr] * oi;
  }
}

// ---------------- global rows, split-K phase A ----------------
__global__ __launch_bounds__(256) void global_attn_part(
    const float* __restrict__ qg, const short* __restrict__ kg,
    const short* __restrict__ vg, float* __restrict__ pml, float* __restrict__ po)
{
  const int ch = blockIdx.x & (NCH - 1);
  const int i  = blockIdx.x >> 4;
  const int h = blockIdx.y, b = blockIdx.z;
  const int tid = threadIdx.x, lane = tid & 63, wid = tid >> 6;

  __shared__ float qrow[64];
  __shared__ float pls[CHK];
  __shared__ float red[8];
  __shared__ float osum[4][64];

  if (tid < 64) qrow[tid] = qg[(size_t)(b * Gc + i) * Dmc + h * HDc + tid];
  __syncthreads();

  const int sk = ch * CHK + tid;
  const s16x8* kr = (const s16x8*)(kg + ((size_t)(b * Sc + sk)) * Dmc + h * HDc);
  float acc = 0.f;
#pragma unroll
  for (int c = 0; c < 8; ++c) {
    s16x8 kv = kr[c];
#pragma unroll
    for (int u = 0; u < 8; ++u) acc = fmaf(qrow[c * 8 + u], b2f(kv[u]), acc);
  }

  float m = acc;
#pragma unroll
  for (int off = 32; off > 0; off >>= 1) m = fmaxf(m, __shfl_xor(m, off));
  if (lane == 0) red[wid] = m;
  __syncthreads();
  m = fmaxf(fmaxf(red[0], red[1]), fmaxf(red[2], red[3]));

  float p = exp2f(acc - m);
  pls[tid] = p;
  float ls = p;
#pragma unroll
  for (int off = 32; off > 0; off >>= 1) ls += __shfl_xor(ls, off);
  if (lane == 0) red[4 + wid] = ls;
  __syncthreads();
  const float l = red[4] + red[5] + red[6] + red[7];

  const int jg = tid >> 3, db = (tid & 7) * 8;
  float o[8] = {};
  const short* vb2 = vg + ((size_t)(b * Sc + ch * CHK + jg * 8)) * Dmc + h * HDc + db;
#pragma unroll
  for (int jj = 0; jj < 8; ++jj) {
    float pw = pls[jg * 8 + jj];
    s16x8 vv = *(const s16x8*)(vb2 + (size_t)jj * Dmc);
#pragma unroll
    for (int u = 0; u < 8; ++u) o[u] = fmaf(pw, b2f(vv[u]), o[u]);
  }
#pragma unroll
  for (int mk = 8; mk <= 32; mk <<= 1)
#pragma unroll
    for (int u = 0; u < 8; ++u) o[u] += __shfl_xor(o[u], mk);
  if ((lane & 56) == 0) {
#pragma unroll
    for (int u = 0; u < 8; ++u) osum[wid][(lane & 7) * 8 + u] = o[u];
  }
  __syncthreads();

  const size_t slot = (((size_t)(b * Hc + h) * Gc + i) * NCH + ch);
  if (tid < 64)
    po[slot * 64 + tid] = osum[0][tid] + osum[1][tid] + osum[2][tid] + osum[3][tid];
  if (tid == 0) { pml[slot * 2] = m; pml[slot * 2 + 1] = l; }
}

// ---------------- global rows, split-K phase B ----------------
__global__ __launch_bounds__(64) void global_attn_comb(
    const float* __restrict__ pml, const float* __restrict__ po,
    float* __restrict__ out)
{
  const int i = blockIdx.x, h = blockIdx.y, b = blockIdx.z;
  const int d = threadIdx.x;
  const size_t base = ((size_t)(b * Hc + h) * Gc + i) * NCH;

  float m = -INFINITY;
#pragma unroll
  for (int ch = 0; ch < NCH; ++ch) m = fmaxf(m, pml[(base + ch) * 2]);
  float l = 0.f, o = 0.f;
#pragma unroll
  for (int ch = 0; ch < NCH; ++ch) {
    float wgt = exp2f(pml[(base + ch) * 2] - m);
    l = fmaf(pml[(base + ch) * 2 + 1], wgt, l);
    o = fmaf(po[(base + ch) * 64 + d], wgt, o);
  }
  out[((size_t)(b * Sc + i)) * Dmc + h * HDc + d] = o / l;
}

extern "C" void kernel_launch(void* const* d_in, const int* in_sizes, int n_in,
                              void* d_out, int out_size, void* d_ws, size_t ws_size,
                              hipStream_t stream) {
  const float* hs  = (const float*)d_in[0];
  const float* Wq  = (const float*)d_in[1];
  const float* bq  = (const float*)d_in[2];
  const float* Wk  = (const float*)d_in[3];
  const float* bk  = (const float*)d_in[4];
  const float* Wv  = (const float*)d_in[5];
  const float* bv  = (const float*)d_in[6];
  const float* Wqg = (const float*)d_in[7];
  const float* bqg = (const float*)d_in[8];
  const float* Wkg = (const float*)d_in[9];
  const float* bkg = (const float*)d_in[10];
  const float* Wvg = (const float*)d_in[11];
  const float* bvg = (const float*)d_in[12];
  float* out = (float*)d_out;

  char* ws = (char*)d_ws;
  const size_t bufB = (size_t)Bc * Sc * Dmc * sizeof(short);   // 12,582,912
  short* hsb = (short*)(ws);
  short* s1  = (short*)(ws + bufB);        // q -> kg
  short* s2  = (short*)(ws + 2 * bufB);    // k -> vg
  short* s3  = (short*)(ws + 3 * bufB);    // v -> {qg,pml,po | Wt_kg,Wt_vg}

  short* wtA = (short*)d_out;              // Wt_{q,k,v} contiguous (d_out free pre-attn)
  short* wtB = wtA + (size_t)Dmc * Dmc;
  short* wtC = wtB + (size_t)Dmc * Dmc;
  float* qg  = (float*)(ws + 3 * bufB);
  float* pml = (float*)(ws + 3 * bufB + 98304);
  float* po  = (float*)(ws + 3 * bufB + 147456);
  short* wtD = (short*)(ws + 3 * bufB + (4u << 20));   // Wt_{kg,vg} contiguous
  short* wtE = wtD + (size_t)Dmc * Dmc;

  dim3 bb(256);
  conv_bf16<<<dim3(3072), bb, 0, stream>>>(hs, hsb);
  transpose_w<<<dim3(24, 24, 3), bb, 0, stream>>>(Wq, Wk, Wv, wtA, wtB, wtC);

  // merged q|k|v projection (q pre-scaled into exp2 domain)
  gemm_fused<<<dim3(64, 36), bb, 0, stream>>>(hsb, wtA, bq, bk, bv, s1, SCALE2q);

  local_attn_mfma<<<dim3(64, Hc, Bc), bb, 0, stream>>>(s1, s2, s3, out);

  transpose_w<<<dim3(24, 24, 2), bb, 0, stream>>>(Wkg, Wvg, Wvg, wtD, wtE, wtE);
  gemm_fused<<<dim3(64, 24), bb, 0, stream>>>(hsb, wtD, bkg, bvg, bvg, s1, 1.0f);

  qg_proj<<<dim3(Bc * Gc, Dmc / 128), bb, 0, stream>>>(hs, Wqg, bqg, qg);
  global_attn_part<<<dim3(Gc * NCH, Hc, Bc), bb, 0, stream>>>(qg, s1, s2, pml, po);
  global_attn_comb<<<dim3(Gc, Hc, Bc), dim3(64), 0, stream>>>(pml, po, out);
}